// Round 3
// baseline (585.426 us; speedup 1.0000x reference)
//
#include <hip/hip_runtime.h>
#include <hip/hip_cooperative_groups.h>
#include <cmath>

namespace cg = cooperative_groups;

#define B_ROWS 16384
#define E_DIM 512
#define H_DIM 1024
#define P_DIM 256
#define K1_RAW 1026
#define K1_PAD 1152   // multiple of 128 -> even number of 64-K tiles

#define NEG_BIG (-3.0e38f)
#define SCL_IN  16.0f            // fp8 pre-scale for A1 and all weights
#define INV_G1  (1.0f / 256.0f)  // GEMM1: A(x16) * W(x16)
#define INV_G   (1.0f / 16.0f)   // GEMM2-4: A(x1) * W(x16)

typedef __attribute__((ext_vector_type(4))) short short4v;
typedef __attribute__((ext_vector_type(8))) short short8v;
typedef __attribute__((ext_vector_type(4))) float f32x4;
typedef __attribute__((ext_vector_type(2))) long long2v;

__device__ __forceinline__ short f2bf(float f) {
    unsigned u = __float_as_uint(f);
    u += 0x7fffu + ((u >> 16) & 1u);   // round-to-nearest-even
    return (short)(u >> 16);
}
__device__ __forceinline__ float bf2f(short s) {
    return __uint_as_float(((unsigned)(unsigned short)s) << 16);
}
// pack 4 floats -> 4 OCP e4m3 bytes (HW cvt, RNE+sat)
__device__ __forceinline__ int pk4_fp8(float a, float b, float c, float d) {
    int v = __builtin_amdgcn_cvt_pk_fp8_f32(a, b, 0, false);
    return  __builtin_amdgcn_cvt_pk_fp8_f32(c, d, v, true);
}

// K-interleave permutation: within each 64-k block, store the 8 eight-byte
// MFMA quad-chunks as [A0 B0 A1 B1 A2 B2 A3 B3] so one b128 read at quad*16
// returns {k-step0 frag, k-step1 frag} for mfma_16x16x32_fp8_fp8.
__device__ __forceinline__ int kperm(int k) {
    return (k & ~63) | (((k >> 3) & 3) << 4) | (((k >> 5) & 1) << 3) | (k & 7);
}

// async global->LDS DMA, 16 B/lane; lds dest = wave-uniform base + lane*16
__device__ __forceinline__ void g2lds16(const void* g, void* l) {
    __builtin_amdgcn_global_load_lds(
        (const __attribute__((address_space(1))) void*)g,
        (__attribute__((address_space(3))) void*)l, 16, 0, 0);
}

// ---------------------------------------------------------------------------
// Phase bodies (device functions), all designed for 256 blocks x 512 threads.
// ---------------------------------------------------------------------------

// prep: one wave per row. Single pass: lane holds 8 x1-floats + 8 x2-floats.
__device__ void prep_row(int row, int lane,
    const float* __restrict__ x1, const float* __restrict__ x2,
    const float* __restrict__ gf, char* __restrict__ A1)
{
    const size_t rb8 = (size_t)row * E_DIM + lane * 8;
    float4 u0 = *(const float4*)&x1[rb8];
    float4 u1 = *(const float4*)&x1[rb8 + 4];
    float4 v0 = *(const float4*)&x2[rb8];
    float4 v1 = *(const float4*)&x2[rb8 + 4];
    float s1 = u0.x*u0.x + u0.y*u0.y + u0.z*u0.z + u0.w*u0.w
             + u1.x*u1.x + u1.y*u1.y + u1.z*u1.z + u1.w*u1.w;
    float s2 = v0.x*v0.x + v0.y*v0.y + v0.z*v0.z + v0.w*v0.w
             + v1.x*v1.x + v1.y*v1.y + v1.z*v1.z + v1.w*v1.w;
    #pragma unroll
    for (int off = 32; off > 0; off >>= 1) {
        s1 += __shfl_xor(s1, off, 64);
        s2 += __shfl_xor(s2, off, 64);
    }
    const float inv1 = SCL_IN / fmaxf(sqrtf(s1), 1e-12f);
    const float inv2 = SCL_IN / fmaxf(sqrtf(s2), 1e-12f);

    const size_t rb = (size_t)row * K1_PAD;
    const int k0 = lane * 8;
    *(int*)&A1[rb + kperm(k0)]           = pk4_fp8(u0.x*inv1, u0.y*inv1, u0.z*inv1, u0.w*inv1);
    *(int*)&A1[rb + kperm(k0 + 4)]       = pk4_fp8(u1.x*inv1, u1.y*inv1, u1.z*inv1, u1.w*inv1);
    *(int*)&A1[rb + kperm(512 + k0)]     = pk4_fp8(v0.x*inv2, v0.y*inv2, v0.z*inv2, v0.w*inv2);
    *(int*)&A1[rb + kperm(512 + k0 + 4)] = pk4_fp8(v1.x*inv2, v1.y*inv2, v1.z*inv2, v1.w*inv2);
    if (lane < 32) {
        const int k = 1024 + lane * 4;
        float a = 0.f, b = 0.f;
        if (k == 1024) { a = gf[(size_t)row * 2 + 0] * SCL_IN;
                         b = gf[(size_t)row * 2 + 1] * SCL_IN; }
        *(int*)&A1[rb + kperm(k)] = pk4_fp8(a, b, 0.f, 0.f);
    }
}

// transpose tiles: job -> (matrix, k0, n0); 256-thread sub-block, own T buffer.
#define NTB_Z0 288   // 18*16
#define NTB_Z1 256
#define NTB_Z2 256
#define NTB_Z3 64
#define NTB_ALL (NTB_Z0 + NTB_Z1 + NTB_Z2 + NTB_Z3)

struct TransJob { const float* W; char* Wt; int K, N, Kpad, k0, n0; };

__device__ __forceinline__ TransJob trans_map(int job,
    const float* W0, char* Wt0, const float* W1, char* Wt1,
    const float* W2, char* Wt2, const float* W3, char* Wt3)
{
    TransJob j;
    if (job < NTB_Z0)                 { j.W = W0; j.Wt = Wt0; j.K = K1_RAW; j.N = H_DIM; j.Kpad = K1_PAD; j.k0 = (job % 18) * 64; j.n0 = (job / 18) * 64; }
    else if (job < NTB_Z0 + NTB_Z1)   { int t2 = job - NTB_Z0;           j.W = W1; j.Wt = Wt1; j.K = H_DIM; j.N = H_DIM; j.Kpad = H_DIM; j.k0 = (t2 & 15) * 64; j.n0 = (t2 >> 4) * 64; }
    else if (job < NTB_Z0 + NTB_Z1 + NTB_Z2) { int t2 = job - NTB_Z0 - NTB_Z1; j.W = W2; j.Wt = Wt2; j.K = H_DIM; j.N = H_DIM; j.Kpad = H_DIM; j.k0 = (t2 & 15) * 64; j.n0 = (t2 >> 4) * 64; }
    else                              { int t2 = job - NTB_Z0 - NTB_Z1 - NTB_Z2; j.W = W3; j.Wt = Wt3; j.K = H_DIM; j.N = P_DIM; j.Kpad = H_DIM; j.k0 = (t2 & 15) * 64; j.n0 = (t2 >> 4) * 64; }
    return j;
}

__device__ void trans_load(const TransJob& j, int tt, float (*T)[68])
{
    const int r = tt >> 4;          // 0..15
    const int c = (tt & 15) << 2;   // 0..60
    #pragma unroll
    for (int rr = 0; rr < 4; ++rr) {
        int k = j.k0 + r + rr * 16;
        float4 v = (k < j.K) ? *(const float4*)&j.W[(size_t)k * j.N + j.n0 + c]
                             : make_float4(0.f, 0.f, 0.f, 0.f);
        v.x *= SCL_IN; v.y *= SCL_IN; v.z *= SCL_IN; v.w *= SCL_IN;
        *(float4*)&T[r + rr * 16][c] = v;
    }
}

__device__ void trans_store(const TransJob& j, int tt, float (*T)[68])
{
    const int n = j.n0 + (tt >> 2);
    const int cn = tt >> 2;
    const int ks = (tt & 3) << 4;   // 0,16,32,48
    #pragma unroll
    for (int g = 0; g < 2; ++g) {
        int kk = ks + g * 8;
        int lo = pk4_fp8(T[kk+0][cn], T[kk+1][cn], T[kk+2][cn], T[kk+3][cn]);
        int hi = pk4_fp8(T[kk+4][cn], T[kk+5][cn], T[kk+6][cn], T[kk+7][cn]);
        int2 o = { lo, hi };
        int np = j.k0 + (((kk >> 3) & 3) << 4) + (((kk >> 5) & 1) << 3);
        *(int2*)&j.Wt[(size_t)n * j.Kpad + np] = o;
    }
}

// ---------------------------------------------------------------------------
// gemm256 body: 256x256-tile 8-phase fp8 GEMM (round-1 proven code, verbatim
// modulo blockIdx remap). blk in [0,256): bx = blk&63 (row), by = blk>>6 (col).
template <int KA>
__device__ void gemm256_body(char* smem, int blk, int t,
    const char* __restrict__ A, const char* __restrict__ Bt,
    const float* __restrict__ bias, float cscale,
    short* __restrict__ Cb, int N)
{
    constexpr int NK = KA >> 6;
    constexpr int NI = NK >> 1;
    static_assert((NK & 1) == 0 && NK >= 4, "need even NK >= 4");

    const int w = t >> 6, lane = t & 63;
    const int wu = __builtin_amdgcn_readfirstlane(w);
    const int wm = w & 1, wn = w >> 1;
    const int m16 = lane & 15, quad = lane >> 4;
    const int row0 = (blk & 63) * 256, col0 = (blk >> 6) * 256;

    const char* AgLo = A  + (size_t)(row0 + wu * 16 + (lane >> 2)) * KA + ((lane & 3) << 4);
    const char* AgHi = AgLo + (size_t)128 * KA;
    const char* BgLo = Bt + (size_t)(col0 + wu * 16 + (lane >> 2)) * KA + ((lane & 3) << 4);
    const char* BgHi = BgLo + (size_t)128 * KA;

    char* const sA0 = smem;
    char* const sB0 = smem + 16384;
    char* const sA1 = smem + 32768;
    char* const sB1 = smem + 49152;

    auto stage = [&](const char* g, size_t ko, char* l) {
        g2lds16(g + ko, l + (wu << 10));
    };

    f32x4 acc[8][4];
    #pragma unroll
    for (int i = 0; i < 8; ++i)
        #pragma unroll
        for (int j = 0; j < 4; ++j)
            acc[i][j] = (f32x4){0.f, 0.f, 0.f, 0.f};

    long2v a[8], b[4];

#define RD_A(SL, LO) do { _Pragma("unroll") for (int ii = 0; ii < 4; ++ii) \
    a[(LO)+ii] = *(const long2v*)&(SL)[(wm*128 + ((LO)+ii)*16 + m16)*64 + quad*16]; } while (0)
#define RD_B(SL, LO) do { _Pragma("unroll") for (int jj = 0; jj < 2; ++jj) \
    b[(LO)+jj] = *(const long2v*)&(SL)[(wn*64 + ((LO)+jj)*16 + m16)*64 + quad*16]; } while (0)
#define QMFMA(I0, J0) do { _Pragma("unroll") for (int ii = 0; ii < 4; ++ii) \
    { _Pragma("unroll") for (int jj = 0; jj < 2; ++jj) { \
        acc[(I0)+ii][(J0)+jj] = __builtin_amdgcn_mfma_f32_16x16x32_fp8_fp8( \
            a[(I0)+ii][0], b[(J0)+jj][0], acc[(I0)+ii][(J0)+jj], 0, 0, 0); \
        acc[(I0)+ii][(J0)+jj] = __builtin_amdgcn_mfma_f32_16x16x32_fp8_fp8( \
            a[(I0)+ii][1], b[(J0)+jj][1], acc[(I0)+ii][(J0)+jj], 0, 0, 0); \
    } } } while (0)
#define BAR  __builtin_amdgcn_s_barrier()
#define PRI1 __builtin_amdgcn_s_setprio(1)
#define PRI0 __builtin_amdgcn_s_setprio(0)

    stage(AgLo, 0, sA0);  stage(AgHi, 0, sA0 + 8192);
    stage(BgLo, 0, sB0);  stage(BgHi, 0, sB0 + 8192);
    stage(AgLo, 64, sA1); stage(AgHi, 64, sA1 + 8192);
    asm volatile("s_waitcnt vmcnt(2)" ::: "memory");
    BAR;

    #pragma unroll 1
    for (int it = 0; it < NI - 1; ++it) {
        const size_t kB1 = (size_t)(2 * it + 1) << 6;
        const size_t kA2 = (size_t)(2 * it + 2) << 6;
        const size_t kA3 = (size_t)(2 * it + 3) << 6;

        RD_A(sA0, 0); RD_B(sB0, 0);
        stage(BgLo, kB1, sB1);
        BAR; PRI1; QMFMA(0, 0); PRI0; BAR;

        RD_A(sA0, 4);
        stage(BgHi, kB1, sB1 + 8192);
        BAR; PRI1; QMFMA(4, 0); PRI0; BAR;

        RD_B(sB0, 2);
        stage(AgLo, kA2, sA0);
        BAR; PRI1; QMFMA(0, 2); PRI0; BAR;

        stage(AgHi, kA2, sA0 + 8192);
        asm volatile("s_waitcnt vmcnt(2)" ::: "memory");
        BAR; PRI1; QMFMA(4, 2); PRI0; BAR;

        RD_A(sA1, 0); RD_B(sB1, 0);
        stage(BgLo, kA2, sB0);
        BAR; PRI1; QMFMA(0, 0); PRI0; BAR;

        RD_A(sA1, 4);
        stage(BgHi, kA2, sB0 + 8192);
        BAR; PRI1; QMFMA(4, 0); PRI0; BAR;

        RD_B(sB1, 2);
        stage(AgLo, kA3, sA1);
        BAR; PRI1; QMFMA(0, 2); PRI0; BAR;

        stage(AgHi, kA3, sA1 + 8192);
        asm volatile("s_waitcnt vmcnt(2)" ::: "memory");
        BAR; PRI1; QMFMA(4, 2); PRI0; BAR;
    }

    {
        const size_t kB1 = (size_t)(NK - 1) << 6;

        RD_A(sA0, 0); RD_B(sB0, 0);
        stage(BgLo, kB1, sB1);
        BAR; PRI1; QMFMA(0, 0); PRI0; BAR;

        RD_A(sA0, 4);
        stage(BgHi, kB1, sB1 + 8192);
        BAR; PRI1; QMFMA(4, 0); PRI0; BAR;

        RD_B(sB0, 2);
        BAR; PRI1; QMFMA(0, 2); PRI0; BAR;

        asm volatile("s_waitcnt vmcnt(0)" ::: "memory");
        BAR; PRI1; QMFMA(4, 2); PRI0; BAR;

        RD_A(sA1, 0); RD_B(sB1, 0);
        BAR; PRI1; QMFMA(0, 0); PRI0; BAR;

        RD_A(sA1, 4);
        BAR; PRI1; QMFMA(4, 0); PRI0; BAR;

        RD_B(sB1, 2);
        BAR; PRI1; QMFMA(0, 2); PRI0; BAR;

        QMFMA(4, 2);
    }

    float bj[4];
    #pragma unroll
    for (int j = 0; j < 4; ++j)
        bj[j] = bias[col0 + wn * 64 + j * 16 + m16];

    short* Cs = (short*)smem;   // [128][264]
    #pragma unroll
    for (int ch = 0; ch < 2; ++ch) {
        __syncthreads();
        if (wm == ch) {
            #pragma unroll
            for (int i = 0; i < 8; ++i) {
                const int rbase = i * 16 + quad * 4;
                #pragma unroll
                for (int j = 0; j < 4; ++j) {
                    const int cc = wn * 64 + j * 16 + m16;
                    #pragma unroll
                    for (int r = 0; r < 4; ++r)
                        Cs[(rbase + r) * 264 + cc] = f2bf(acc[i][j][r] * cscale + bj[j]);
                }
            }
        }
        __syncthreads();
        #pragma unroll
        for (int p = 0; p < 8; ++p) {
            const int idx = p * 512 + t;
            const int r = idx >> 5, c8 = idx & 31;
            short8v v = *(const short8v*)&Cs[r * 264 + c8 * 8];
            *(short8v*)&Cb[(size_t)(row0 + ch * 128 + r) * N + col0 + c8 * 8] = v;
        }
    }
    __syncthreads();
#undef RD_A
#undef RD_B
#undef QMFMA
}

// ---------------------------------------------------------------------------
// LN+ReLU per row (one wave per row). bf16 in, fp8(kperm) out + optional bf16.
template <int HAS_RES, int WRITE_BF>
__device__ void ln_row(int row, int lane,
    const short* __restrict__ X, const float* __restrict__ gamma,
    const float* __restrict__ beta, const short* __restrict__ res,
    char* __restrict__ act, short* __restrict__ resout)
{
    const size_t base = (size_t)row * H_DIM;

    float y[4][4];
    float s = 0.f, ss = 0.f;
    #pragma unroll
    for (int j = 0; j < 4; ++j) {
        const int idx = j * 256 + lane * 4;
        short4v xb = *(const short4v*)&X[base + idx];
        #pragma unroll
        for (int e = 0; e < 4; ++e) {
            float xv = bf2f(xb[e]);
            y[j][e] = xv;
            s += xv; ss += xv * xv;
        }
    }
    #pragma unroll
    for (int off = 32; off > 0; off >>= 1) {
        s  += __shfl_xor(s,  off, 64);
        ss += __shfl_xor(ss, off, 64);
    }
    const float m = s * (1.f / H_DIM);
    const float var = fmaxf(ss * (1.f / H_DIM) - m * m, 0.f);
    const float r = 1.f / sqrtf(var + 1e-5f);

    #pragma unroll
    for (int j = 0; j < 4; ++j) {
        const int idx = j * 256 + lane * 4;
        float4 g  = *(const float4*)&gamma[idx];
        float4 be = *(const float4*)&beta[idx];
        float gv[4] = { g.x, g.y, g.z, g.w };
        float bv[4] = { be.x, be.y, be.z, be.w };
        #pragma unroll
        for (int e = 0; e < 4; ++e)
            y[j][e] = fmaxf((y[j][e] - m) * r * gv[e] + bv[e], 0.f);
        if (HAS_RES) {
            short4v rr = *(const short4v*)&res[base + idx];
            #pragma unroll
            for (int e = 0; e < 4; ++e) y[j][e] += bf2f(rr[e]);
        }
        *(int*)&act[base + kperm(idx)] = pk4_fp8(y[j][0], y[j][1], y[j][2], y[j][3]);
        if (WRITE_BF) {
            short4v o = { f2bf(y[j][0]), f2bf(y[j][1]), f2bf(y[j][2]), f2bf(y[j][3]) };
            *(short4v*)&resout[base + idx] = o;
        }
    }
}

// ---------------------------------------------------------------------------
// G4: 64x256 tile (full N=P_DIM), A+B LDS-staged m97-style loop, fused
// final-LN + classifier + gender-mask epilogue. 8 waves: wm=w&1 (32-row
// half), wn=w>>1 (64-col quarter). acc[2][4].
__device__ void gemm_final_cls(char* smem, int blk, int t,
    const char* __restrict__ A, const char* __restrict__ Bt,
    const float* __restrict__ bias, const float* __restrict__ gamma,
    const float* __restrict__ beta, const float* __restrict__ Wc,
    const float* __restrict__ bc, const float* __restrict__ gfeat,
    float* __restrict__ outp)
{
    const int w = t >> 6, lane = t & 63;
    const int wu = __builtin_amdgcn_readfirstlane(w);
    const int wm = w & 1, wn = w >> 1;
    const int m16 = lane & 15, quad = lane >> 4;
    const int row0 = blk * 64;

    char* const sA = smem;            // [2][4096]
    char* const sB = smem + 8192;     // [2][16384]

    const char* Ag  = A  + (size_t)(row0 + (wu & 3) * 16 + (lane >> 2)) * H_DIM + ((lane & 3) << 4);
    const char* Bg0 = Bt + (size_t)(wu * 32 + (lane >> 2)) * H_DIM + ((lane & 3) << 4);
    const char* Bg1 = Bg0 + (size_t)16 * H_DIM;

    auto stage = [&](int kt, int bi) {
        const size_t ko = (size_t)kt << 6;
        if (wu < 4) g2lds16(Ag + ko, sA + bi * 4096 + ((wu & 3) << 10));
        g2lds16(Bg0 + ko, sB + bi * 16384 + wu * 2048);
        g2lds16(Bg1 + ko, sB + bi * 16384 + wu * 2048 + 1024);
    };

    f32x4 acc[2][4];
    #pragma unroll
    for (int i = 0; i < 2; ++i)
        #pragma unroll
        for (int j = 0; j < 4; ++j)
            acc[i][j] = (f32x4){0.f, 0.f, 0.f, 0.f};

    stage(0, 0);
    #pragma unroll 1
    for (int kt = 0; kt < 16; ++kt) {
        asm volatile("s_waitcnt vmcnt(0)\n\ts_barrier" ::: "memory");
        if (kt + 1 < 16) stage(kt + 1, (kt + 1) & 1);
        const char* As = sA + (kt & 1) * 4096;
        const char* Bs = sB + (kt & 1) * 16384;
        long2v af[2], bf[4];
        #pragma unroll
        for (int i = 0; i < 2; ++i)
            af[i] = *(const long2v*)&As[(wm * 32 + i * 16 + m16) * 64 + quad * 16];
        #pragma unroll
        for (int j = 0; j < 4; ++j)
            bf[j] = *(const long2v*)&Bs[(wn * 64 + j * 16 + m16) * 64 + quad * 16];
        #pragma unroll
        for (int i = 0; i < 2; ++i)
            #pragma unroll
            for (int j = 0; j < 4; ++j) {
                acc[i][j] = __builtin_amdgcn_mfma_f32_16x16x32_fp8_fp8(
                    af[i][0], bf[j][0], acc[i][j], 0, 0, 0);
                acc[i][j] = __builtin_amdgcn_mfma_f32_16x16x32_fp8_fp8(
                    af[i][1], bf[j][1], acc[i][j], 0, 0, 0);
            }
    }
    __syncthreads();   // all LDS reads done before smem reuse

    float bj[4];
    #pragma unroll
    for (int j = 0; j < 4; ++j)
        bj[j] = bias[wn * 64 + j * 16 + m16];

    short* xs  = (short*)smem;                 // [64][264] bf16
    float* red = (float*)(smem + 33792);       // [8][64][2]
    float* mr  = (float*)(smem + 37888);       // [64][2]

    // per-row partial stats (this wave covers rows wm*32..+31, cols wn*64..+63)
    #pragma unroll
    for (int i = 0; i < 2; ++i)
        #pragma unroll
        for (int r = 0; r < 4; ++r) {
            float s = 0.f, ss = 0.f;
            #pragma unroll
            for (int j = 0; j < 4; ++j) {
                float x = acc[i][j][r] * INV_G + bj[j];
                s += x; ss += x * x;
            }
            #pragma unroll
            for (int off = 1; off <= 8; off <<= 1) {
                s  += __shfl_xor(s,  off, 64);
                ss += __shfl_xor(ss, off, 64);
            }
            if (m16 == 0) {
                const int ri = wm * 32 + i * 16 + quad * 4 + r;
                red[(w * 64 + ri) * 2 + 0] = s;
                red[(w * 64 + ri) * 2 + 1] = ss;
            }
        }
    __syncthreads();
    if (t < 64) {
        const int wmRow = t >> 5;
        float s = 0.f, ss = 0.f;
        #pragma unroll
        for (int q = 0; q < 4; ++q) {
            const int ww = wmRow + 2 * q;
            s  += red[(ww * 64 + t) * 2 + 0];
            ss += red[(ww * 64 + t) * 2 + 1];
        }
        const float mm = s * (1.f / P_DIM);
        mr[t * 2 + 0] = mm;
        mr[t * 2 + 1] = 1.f / sqrtf(fmaxf(ss * (1.f / P_DIM) - mm * mm, 0.f) + 1e-5f);
    }
    // bf16 re-layout (xs region disjoint from red/mr)
    #pragma unroll
    for (int i = 0; i < 2; ++i)
        #pragma unroll
        for (int j = 0; j < 4; ++j)
            #pragma unroll
            for (int r = 0; r < 4; ++r)
                xs[(wm * 32 + i * 16 + quad * 4 + r) * 264 + wn * 64 + j * 16 + m16] =
                    f2bf(acc[i][j][r] * INV_G + bj[j]);
    __syncthreads();

    // classifier: 8 rows per wave
    #pragma unroll 2
    for (int rr = 0; rr < 8; ++rr) {
        const int row = w * 8 + rr;
        const float mm = mr[row * 2 + 0], rs = mr[row * 2 + 1];
        const int c = lane * 4;
        short4v xv = *(const short4v*)&xs[row * 264 + c];
        float4 ga = *(const float4*)&gamma[c];
        float4 ba = *(const float4*)&beta[c];
        const float gv[4] = {ga.x, ga.y, ga.z, ga.w};
        const float bvv[4] = {ba.x, ba.y, ba.z, ba.w};
        float p[7] = {0.f, 0.f, 0.f, 0.f, 0.f, 0.f, 0.f};
        #pragma unroll
        for (int e = 0; e < 4; ++e) {
            const float yv = fmaxf((bf2f(xv[e]) - mm) * rs * gv[e] + bvv[e], 0.f);
            const float* wr = &Wc[(c + e) * 7];
            #pragma unroll
            for (int c7 = 0; c7 < 7; ++c7) p[c7] += yv * wr[c7];
        }
        #pragma unroll
        for (int off = 32; off > 0; off >>= 1)
            #pragma unroll
            for (int c7 = 0; c7 < 7; ++c7) p[c7] += __shfl_xor(p[c7], off, 64);
        if (lane == 0) {
            const size_t gr = (size_t)(row0 + row);
            int g1 = (gfeat[gr * 2 + 0] != 0.f);
            int g2 = (gfeat[gr * 2 + 1] != 0.f);
            unsigned bits = (g1 == g2) ? (g1 ? 0x24u : 0x12u) : 0x49u;
            #pragma unroll
            for (int c7 = 0; c7 < 7; ++c7)
                outp[gr * 7 + c7] = ((bits >> c7) & 1u) ? p[c7] + bc[c7] : NEG_BIG;
        }
    }
}

// ---------------------------------------------------------------------------
struct P21 {
    const float *x1, *x2, *gf;
    const float *W_in, *b_in, *g_in, *be_in;
    const float *W_r1, *b_r1, *g_r1, *be_r1;
    const float *W_r2, *b_r2, *g_r2, *be_r2;
    const float *W_f,  *b_f,  *g_f,  *be_f;
    const float *W_c,  *b_c;
    float* out;
    char *A1, *act, *Wt_in, *Wt_r1, *Wt_r2, *Wt_f;
    short *fb, *preb;
};

__global__ __launch_bounds__(512, 2) void fused_all(P21 p)
{
    cg::grid_group grid = cg::this_grid();
    __shared__ __align__(16) char smem[67584];

    const int blk = blockIdx.x;
    const int t = threadIdx.x;
    const int w = t >> 6, lane = t & 63;

    // ---- P0: prep (wave per row) + weight transposes ----
    #pragma unroll 2
    for (int rr = 0; rr < 8; ++rr)
        prep_row(blk * 64 + w * 8 + rr, lane, p.x1, p.x2, p.gf, p.A1);

    {
        const int sub = t >> 8;          // 0/1
        const int tt  = t & 255;
        float (*T)[68] = (float (*)[68])(smem + sub * 17408);
        #pragma unroll 1
        for (int pp = 0; pp < 2; ++pp) {
            const int job = blk * 4 + pp * 2 + sub;
            const bool active = job < NTB_ALL;
            TransJob j;
            if (active) { j = trans_map(job, p.W_in, p.Wt_in, p.W_r1, p.Wt_r1,
                                        p.W_r2, p.Wt_r2, p.W_f, p.Wt_f);
                          trans_load(j, tt, T); }
            __syncthreads();
            if (active) trans_store(j, tt, T);
            __syncthreads();
        }
    }
    grid.sync();

    // ---- P1: input_proj GEMM ----
    gemm256_body<K1_PAD>(smem, blk, t, p.A1, p.Wt_in, p.b_in, INV_G1, p.preb, H_DIM);
    grid.sync();

    // ---- P2: LN1 -> act fp8 + fb bf16 ----
    #pragma unroll 2
    for (int rr = 0; rr < 8; ++rr)
        ln_row<0, 1>(blk * 64 + w * 8 + rr, lane, p.preb, p.g_in, p.be_in,
                     nullptr, p.act, p.fb);
    grid.sync();

    // ---- P3: residual GEMM 1 ----
    gemm256_body<H_DIM>(smem, blk, t, p.act, p.Wt_r1, p.b_r1, INV_G, p.preb, H_DIM);
    grid.sync();

    // ---- P4: LN2 (+res) ----
    #pragma unroll 2
    for (int rr = 0; rr < 8; ++rr)
        ln_row<1, 1>(blk * 64 + w * 8 + rr, lane, p.preb, p.g_r1, p.be_r1,
                     p.fb, p.act, p.fb);
    grid.sync();

    // ---- P5: residual GEMM 2 ----
    gemm256_body<H_DIM>(smem, blk, t, p.act, p.Wt_r2, p.b_r2, INV_G, p.preb, H_DIM);
    grid.sync();

    // ---- P6: LN3 (+res, no bf16 out) ----
    #pragma unroll 2
    for (int rr = 0; rr < 8; ++rr)
        ln_row<1, 0>(blk * 64 + w * 8 + rr, lane, p.preb, p.g_r2, p.be_r2,
                     p.fb, p.act, nullptr);
    grid.sync();

    // ---- P7: final_proj + final LN + classifier + mask ----
    gemm_final_cls(smem, blk, t, p.act, p.Wt_f, p.b_f, p.g_f, p.be_f,
                   p.W_c, p.b_c, p.gf, p.out);
}

// ---------------------------------------------------------------------------
extern "C" void kernel_launch(void* const* d_in, const int* in_sizes, int n_in,
                              void* d_out, int out_size, void* d_ws, size_t ws_size,
                              hipStream_t stream)
{
    P21 p;
    p.x1   = (const float*)d_in[0];
    p.x2   = (const float*)d_in[1];
    p.gf   = (const float*)d_in[2];
    p.W_in = (const float*)d_in[3];
    p.b_in = (const float*)d_in[4];
    p.g_in = (const float*)d_in[5];
    p.be_in = (const float*)d_in[6];
    p.W_r1 = (const float*)d_in[7];
    p.b_r1 = (const float*)d_in[8];
    p.g_r1 = (const float*)d_in[9];
    p.be_r1 = (const float*)d_in[10];
    p.W_r2 = (const float*)d_in[11];
    p.b_r2 = (const float*)d_in[12];
    p.g_r2 = (const float*)d_in[13];
    p.be_r2 = (const float*)d_in[14];
    p.W_f  = (const float*)d_in[15];
    p.b_f  = (const float*)d_in[16];
    p.g_f  = (const float*)d_in[17];
    p.be_f = (const float*)d_in[18];
    p.W_c  = (const float*)d_in[19];
    p.b_c  = (const float*)d_in[20];
    p.out  = (float*)d_out;

    const int B = B_ROWS;
    char* q = (char*)d_ws;
    p.A1    = q;          q += (size_t)B * K1_PAD;
    p.act   = q;          q += (size_t)B * H_DIM;
    p.fb    = (short*)q;  q += (size_t)B * H_DIM * 2;
    p.preb  = (short*)q;  q += (size_t)B * H_DIM * 2;
    p.Wt_in = q;          q += (size_t)H_DIM * K1_PAD;
    p.Wt_r1 = q;          q += (size_t)H_DIM * H_DIM;
    p.Wt_r2 = q;          q += (size_t)H_DIM * H_DIM;
    p.Wt_f  = q;          q += (size_t)P_DIM * H_DIM;

    void* kargs[] = { (void*)&p };
    hipLaunchCooperativeKernel((void*)fused_all, dim3(256), dim3(512),
                               kargs, 0, stream);
}

// Round 5
// 294.788 us; speedup vs baseline: 1.9859x; 1.9859x over previous
//
#include <hip/hip_runtime.h>
#include <cmath>

#define B_ROWS 16384
#define E_DIM 512
#define H_DIM 1024
#define P_DIM 256
#define K1_RAW 1026
#define K1_PAD 1152   // multiple of 128 -> even number of 64-K tiles

#define NEG_BIG (-3.0e38f)
#define SCL_IN  16.0f            // fp8 pre-scale for A1 and all weights
#define INV_G1  (1.0f / 256.0f)  // GEMM1: A(x16) * W(x16)
#define INV_G   (1.0f / 16.0f)   // GEMM2-4: A(x1) * W(x16)

typedef __attribute__((ext_vector_type(4))) short short4v;
typedef __attribute__((ext_vector_type(8))) short short8v;
typedef __attribute__((ext_vector_type(4))) float f32x4;
typedef __attribute__((ext_vector_type(2))) long long2v;

__device__ __forceinline__ short f2bf(float f) {
    unsigned u = __float_as_uint(f);
    u += 0x7fffu + ((u >> 16) & 1u);   // round-to-nearest-even
    return (short)(u >> 16);
}
__device__ __forceinline__ float bf2f(short s) {
    return __uint_as_float(((unsigned)(unsigned short)s) << 16);
}
// pack 4 floats -> 4 OCP e4m3 bytes (HW cvt, RNE+sat)
__device__ __forceinline__ int pk4_fp8(float a, float b, float c, float d) {
    int v = __builtin_amdgcn_cvt_pk_fp8_f32(a, b, 0, false);
    return  __builtin_amdgcn_cvt_pk_fp8_f32(c, d, v, true);
}

// K-interleave permutation: within each 64-k block, store the 8 eight-byte
// MFMA quad-chunks as [A0 B0 A1 B1 A2 B2 A3 B3] so one b128 read at quad*16
// returns {k-step0 frag, k-step1 frag} for mfma_16x16x32_fp8_fp8.
__device__ __forceinline__ int kperm(int k) {
    return (k & ~63) | (((k >> 3) & 3) << 4) | (((k >> 5) & 1) << 3) | (k & 7);
}

// async global->LDS DMA, 16 B/lane; lds dest = wave-uniform base + lane*16
__device__ __forceinline__ void g2lds16(const void* g, void* l) {
    __builtin_amdgcn_global_load_lds(
        (const __attribute__((address_space(1))) void*)g,
        (__attribute__((address_space(3))) void*)l, 16, 0, 0);
}

// ---------------------------------------------------------------------------
// prep_trans: blocks [0, B/4): per-row L2 norm + fp8 A1 emit, one wave per
// row (single global read). Blocks [B/4, B/4+864): weight transpose+cvt.
#define NTB_Z0 288   // 18*16
#define NTB_Z1 256
#define NTB_Z2 256
#define NTB_Z3 64
#define NTB_ALL (NTB_Z0 + NTB_Z1 + NTB_Z2 + NTB_Z3)
#define PREP_BLKS (B_ROWS / 4)

__global__ __launch_bounds__(256) void prep_trans(
    const float* __restrict__ x1, const float* __restrict__ x2,
    const float* __restrict__ gf, char* __restrict__ A1,
    const float* __restrict__ W0, char* __restrict__ Wt0,
    const float* __restrict__ W1, char* __restrict__ Wt1,
    const float* __restrict__ W2, char* __restrict__ Wt2,
    const float* __restrict__ W3, char* __restrict__ Wt3)
{
    __shared__ float T[64][68];
    const int t = threadIdx.x;
    const int bid = blockIdx.x;

    if (bid < PREP_BLKS) {
        const int lane = t & 63;
        const int row = bid * 4 + (t >> 6);
        const size_t rb8 = (size_t)row * E_DIM + lane * 8;
        float4 u0 = *(const float4*)&x1[rb8];
        float4 u1 = *(const float4*)&x1[rb8 + 4];
        float4 v0 = *(const float4*)&x2[rb8];
        float4 v1 = *(const float4*)&x2[rb8 + 4];
        float s1 = u0.x*u0.x + u0.y*u0.y + u0.z*u0.z + u0.w*u0.w
                 + u1.x*u1.x + u1.y*u1.y + u1.z*u1.z + u1.w*u1.w;
        float s2 = v0.x*v0.x + v0.y*v0.y + v0.z*v0.z + v0.w*v0.w
                 + v1.x*v1.x + v1.y*v1.y + v1.z*v1.z + v1.w*v1.w;
        #pragma unroll
        for (int off = 32; off > 0; off >>= 1) {
            s1 += __shfl_xor(s1, off, 64);
            s2 += __shfl_xor(s2, off, 64);
        }
        const float inv1 = SCL_IN / fmaxf(sqrtf(s1), 1e-12f);
        const float inv2 = SCL_IN / fmaxf(sqrtf(s2), 1e-12f);

        const size_t rb = (size_t)row * K1_PAD;
        const int k0 = lane * 8;
        *(int*)&A1[rb + kperm(k0)]           = pk4_fp8(u0.x*inv1, u0.y*inv1, u0.z*inv1, u0.w*inv1);
        *(int*)&A1[rb + kperm(k0 + 4)]       = pk4_fp8(u1.x*inv1, u1.y*inv1, u1.z*inv1, u1.w*inv1);
        *(int*)&A1[rb + kperm(512 + k0)]     = pk4_fp8(v0.x*inv2, v0.y*inv2, v0.z*inv2, v0.w*inv2);
        *(int*)&A1[rb + kperm(512 + k0 + 4)] = pk4_fp8(v1.x*inv2, v1.y*inv2, v1.z*inv2, v1.w*inv2);
        if (lane < 32) {
            const int k = 1024 + lane * 4;
            float a = 0.f, b = 0.f;
            if (k == 1024) { a = gf[(size_t)row * 2 + 0] * SCL_IN;
                             b = gf[(size_t)row * 2 + 1] * SCL_IN; }
            *(int*)&A1[rb + kperm(k)] = pk4_fp8(a, b, 0.f, 0.f);
        }
        return;
    }

    // ---- transpose body ----
    int job = bid - PREP_BLKS;
    const float* W; char* Wt; int K, N, Kpad, k0, n0;
    if (job < NTB_Z0)                 { W = W0; Wt = Wt0; K = K1_RAW; N = H_DIM; Kpad = K1_PAD; k0 = (job % 18) * 64; n0 = (job / 18) * 64; }
    else if (job < NTB_Z0 + NTB_Z1)   { int t2 = job - NTB_Z0;           W = W1; Wt = Wt1; K = H_DIM; N = H_DIM; Kpad = H_DIM; k0 = (t2 & 15) * 64; n0 = (t2 >> 4) * 64; }
    else if (job < NTB_Z0 + NTB_Z1 + NTB_Z2) { int t2 = job - NTB_Z0 - NTB_Z1; W = W2; Wt = Wt2; K = H_DIM; N = H_DIM; Kpad = H_DIM; k0 = (t2 & 15) * 64; n0 = (t2 >> 4) * 64; }
    else                              { int t2 = job - NTB_Z0 - NTB_Z1 - NTB_Z2; W = W3; Wt = Wt3; K = H_DIM; N = P_DIM; Kpad = H_DIM; k0 = (t2 & 15) * 64; n0 = (t2 >> 4) * 64; }

    const int r = t >> 4;          // 0..15
    const int c = (t & 15) << 2;   // 0..60
    #pragma unroll
    for (int rr = 0; rr < 4; ++rr) {
        int k = k0 + r + rr * 16;
        float4 v = (k < K) ? *(const float4*)&W[(size_t)k * N + n0 + c]
                           : make_float4(0.f, 0.f, 0.f, 0.f);
        v.x *= SCL_IN; v.y *= SCL_IN; v.z *= SCL_IN; v.w *= SCL_IN;
        *(float4*)&T[r + rr * 16][c] = v;
    }
    __syncthreads();
    const int n = n0 + (t >> 2);
    const int cn = t >> 2;
    const int ks = (t & 3) << 4;   // 0,16,32,48
    #pragma unroll
    for (int g = 0; g < 2; ++g) {
        int kk = ks + g * 8;
        int lo = pk4_fp8(T[kk+0][cn], T[kk+1][cn], T[kk+2][cn], T[kk+3][cn]);
        int hi = pk4_fp8(T[kk+4][cn], T[kk+5][cn], T[kk+6][cn], T[kk+7][cn]);
        int2 o = { lo, hi };
        int np = k0 + (((kk >> 3) & 3) << 4) + (((kk >> 5) & 1) << 3);
        *(int2*)&Wt[(size_t)n * Kpad + np] = o;
    }
}

// ---------------------------------------------------------------------------
// gemm256_f8: 256x256-tile 8-phase fp8 GEMM (round-1 proven, verbatim).
template <int KA>
__global__ __launch_bounds__(512, 2) void gemm256_f8(
    const char* __restrict__ A, const char* __restrict__ Bt,
    const float* __restrict__ bias, float cscale,
    short* __restrict__ Cb, int N)
{
    constexpr int NK = KA >> 6;
    constexpr int NI = NK >> 1;
    static_assert((NK & 1) == 0 && NK >= 4, "need even NK >= 4");
    constexpr int LDSZ = 128 * 264 * 2 > 65536 ? 128 * 264 * 2 : 65536;

    __shared__ __align__(16) char smem[LDSZ];

    const int t = threadIdx.x;
    const int w = t >> 6, lane = t & 63;
    const int wu = __builtin_amdgcn_readfirstlane(w);
    const int wm = w & 1, wn = w >> 1;
    const int m16 = lane & 15, quad = lane >> 4;
    const int row0 = blockIdx.x * 256, col0 = blockIdx.y * 256;

    const char* AgLo = A  + (size_t)(row0 + wu * 16 + (lane >> 2)) * KA + ((lane & 3) << 4);
    const char* AgHi = AgLo + (size_t)128 * KA;
    const char* BgLo = Bt + (size_t)(col0 + wu * 16 + (lane >> 2)) * KA + ((lane & 3) << 4);
    const char* BgHi = BgLo + (size_t)128 * KA;

    char* const sA0 = smem;
    char* const sB0 = smem + 16384;
    char* const sA1 = smem + 32768;
    char* const sB1 = smem + 49152;

    auto stage = [&](const char* g, size_t ko, char* l) {
        g2lds16(g + ko, l + (wu << 10));
    };

    f32x4 acc[8][4];
    #pragma unroll
    for (int i = 0; i < 8; ++i)
        #pragma unroll
        for (int j = 0; j < 4; ++j)
            acc[i][j] = (f32x4){0.f, 0.f, 0.f, 0.f};

    long2v a[8], b[4];

#define RD_A(SL, LO) do { _Pragma("unroll") for (int ii = 0; ii < 4; ++ii) \
    a[(LO)+ii] = *(const long2v*)&(SL)[(wm*128 + ((LO)+ii)*16 + m16)*64 + quad*16]; } while (0)
#define RD_B(SL, LO) do { _Pragma("unroll") for (int jj = 0; jj < 2; ++jj) \
    b[(LO)+jj] = *(const long2v*)&(SL)[(wn*64 + ((LO)+jj)*16 + m16)*64 + quad*16]; } while (0)
#define QMFMA(I0, J0) do { _Pragma("unroll") for (int ii = 0; ii < 4; ++ii) \
    { _Pragma("unroll") for (int jj = 0; jj < 2; ++jj) { \
        acc[(I0)+ii][(J0)+jj] = __builtin_amdgcn_mfma_f32_16x16x32_fp8_fp8( \
            a[(I0)+ii][0], b[(J0)+jj][0], acc[(I0)+ii][(J0)+jj], 0, 0, 0); \
        acc[(I0)+ii][(J0)+jj] = __builtin_amdgcn_mfma_f32_16x16x32_fp8_fp8( \
            a[(I0)+ii][1], b[(J0)+jj][1], acc[(I0)+ii][(J0)+jj], 0, 0, 0); \
    } } } while (0)
#define BAR  __builtin_amdgcn_s_barrier()
#define PRI1 __builtin_amdgcn_s_setprio(1)
#define PRI0 __builtin_amdgcn_s_setprio(0)

    stage(AgLo, 0, sA0);  stage(AgHi, 0, sA0 + 8192);
    stage(BgLo, 0, sB0);  stage(BgHi, 0, sB0 + 8192);
    stage(AgLo, 64, sA1); stage(AgHi, 64, sA1 + 8192);
    asm volatile("s_waitcnt vmcnt(2)" ::: "memory");
    BAR;

    #pragma unroll 1
    for (int it = 0; it < NI - 1; ++it) {
        const size_t kB1 = (size_t)(2 * it + 1) << 6;
        const size_t kA2 = (size_t)(2 * it + 2) << 6;
        const size_t kA3 = (size_t)(2 * it + 3) << 6;

        RD_A(sA0, 0); RD_B(sB0, 0);
        stage(BgLo, kB1, sB1);
        BAR; PRI1; QMFMA(0, 0); PRI0; BAR;

        RD_A(sA0, 4);
        stage(BgHi, kB1, sB1 + 8192);
        BAR; PRI1; QMFMA(4, 0); PRI0; BAR;

        RD_B(sB0, 2);
        stage(AgLo, kA2, sA0);
        BAR; PRI1; QMFMA(0, 2); PRI0; BAR;

        stage(AgHi, kA2, sA0 + 8192);
        asm volatile("s_waitcnt vmcnt(2)" ::: "memory");
        BAR; PRI1; QMFMA(4, 2); PRI0; BAR;

        RD_A(sA1, 0); RD_B(sB1, 0);
        stage(BgLo, kA2, sB0);
        BAR; PRI1; QMFMA(0, 0); PRI0; BAR;

        RD_A(sA1, 4);
        stage(BgHi, kA2, sB0 + 8192);
        BAR; PRI1; QMFMA(4, 0); PRI0; BAR;

        RD_B(sB1, 2);
        stage(AgLo, kA3, sA1);
        BAR; PRI1; QMFMA(0, 2); PRI0; BAR;

        stage(AgHi, kA3, sA1 + 8192);
        asm volatile("s_waitcnt vmcnt(2)" ::: "memory");
        BAR; PRI1; QMFMA(4, 2); PRI0; BAR;
    }

    {
        const size_t kB1 = (size_t)(NK - 1) << 6;

        RD_A(sA0, 0); RD_B(sB0, 0);
        stage(BgLo, kB1, sB1);
        BAR; PRI1; QMFMA(0, 0); PRI0; BAR;

        RD_A(sA0, 4);
        stage(BgHi, kB1, sB1 + 8192);
        BAR; PRI1; QMFMA(4, 0); PRI0; BAR;

        RD_B(sB0, 2);
        BAR; PRI1; QMFMA(0, 2); PRI0; BAR;

        asm volatile("s_waitcnt vmcnt(0)" ::: "memory");
        BAR; PRI1; QMFMA(4, 2); PRI0; BAR;

        RD_A(sA1, 0); RD_B(sB1, 0);
        BAR; PRI1; QMFMA(0, 0); PRI0; BAR;

        RD_A(sA1, 4);
        BAR; PRI1; QMFMA(4, 0); PRI0; BAR;

        RD_B(sB1, 2);
        BAR; PRI1; QMFMA(0, 2); PRI0; BAR;

        QMFMA(4, 2);
    }

    float bj[4];
    #pragma unroll
    for (int j = 0; j < 4; ++j)
        bj[j] = bias[col0 + wn * 64 + j * 16 + m16];

    short* Cs = (short*)smem;   // [128][264]
    #pragma unroll
    for (int ch = 0; ch < 2; ++ch) {
        __syncthreads();
        if (wm == ch) {
            #pragma unroll
            for (int i = 0; i < 8; ++i) {
                const int rbase = i * 16 + quad * 4;
                #pragma unroll
                for (int j = 0; j < 4; ++j) {
                    const int cc = wn * 64 + j * 16 + m16;
                    #pragma unroll
                    for (int r = 0; r < 4; ++r)
                        Cs[(rbase + r) * 264 + cc] = f2bf(acc[i][j][r] * cscale + bj[j]);
                }
            }
        }
        __syncthreads();
        #pragma unroll
        for (int p = 0; p < 8; ++p) {
            const int idx = p * 512 + t;
            const int r = idx >> 5, c8 = idx & 31;
            short8v v = *(const short8v*)&Cs[r * 264 + c8 * 8];
            *(short8v*)&Cb[(size_t)(row0 + ch * 128 + r) * N + col0 + c8 * 8] = v;
        }
    }
#undef RD_A
#undef RD_B
#undef QMFMA
#undef BAR
#undef PRI1
#undef PRI0
}

// ---------------------------------------------------------------------------
// LN+ReLU, ONE WAVE PER ROW (4 rows/block). bf16 in, fp8(kperm) out.
// Residual carry reconstructed from the PREVIOUS fp8 act (in-place buffer):
// each thread reads its own int32 (4 fp8 bytes) before overwriting it.
template <int HAS_RES>
__global__ __launch_bounds__(256) void ln_relu_f8(
    const short* __restrict__ X, const float* __restrict__ gamma,
    const float* __restrict__ beta, char* __restrict__ act)
{
    const int row  = blockIdx.x * 4 + (threadIdx.x >> 6);
    const int lane = threadIdx.x & 63;
    const size_t base = (size_t)row * H_DIM;

    float y[4][4];
    float s = 0.f, ss = 0.f;
    #pragma unroll
    for (int j = 0; j < 4; ++j) {
        const int idx = j * 256 + lane * 4;
        short4v xb = *(const short4v*)&X[base + idx];
        #pragma unroll
        for (int e = 0; e < 4; ++e) {
            float xv = bf2f(xb[e]);
            y[j][e] = xv;
            s += xv; ss += xv * xv;
        }
    }
    #pragma unroll
    for (int off = 32; off > 0; off >>= 1) {
        s  += __shfl_xor(s,  off, 64);
        ss += __shfl_xor(ss, off, 64);
    }
    const float m = s * (1.f / H_DIM);
    const float var = fmaxf(ss * (1.f / H_DIM) - m * m, 0.f);
    const float r = 1.f / sqrtf(var + 1e-5f);

    #pragma unroll
    for (int j = 0; j < 4; ++j) {
        const int idx = j * 256 + lane * 4;
        float4 g  = *(const float4*)&gamma[idx];
        float4 be = *(const float4*)&beta[idx];
        float gv[4] = { g.x, g.y, g.z, g.w };
        float bv[4] = { be.x, be.y, be.z, be.w };
        #pragma unroll
        for (int e = 0; e < 4; ++e)
            y[j][e] = fmaxf((y[j][e] - m) * r * gv[e] + bv[e], 0.f);
        if constexpr (HAS_RES) {
            const int rv = *(const int*)&act[base + kperm(idx)];
            y[j][0] += __builtin_amdgcn_cvt_f32_fp8(rv, 0);
            y[j][1] += __builtin_amdgcn_cvt_f32_fp8(rv, 1);
            y[j][2] += __builtin_amdgcn_cvt_f32_fp8(rv, 2);
            y[j][3] += __builtin_amdgcn_cvt_f32_fp8(rv, 3);
        }
        *(int*)&act[base + kperm(idx)] = pk4_fp8(y[j][0], y[j][1], y[j][2], y[j][3]);
    }
}

// ---------------------------------------------------------------------------
// gemm_fcls: final_proj GEMM (64x256 tile, full N=P_DIM) + fused final LN +
// classifier + gender mask. Grid 256 x 512 thr. (Logic verified in round 3.)
__global__ __launch_bounds__(512, 2) void gemm_fcls(
    const char* __restrict__ A, const char* __restrict__ Bt,
    const float* __restrict__ bias, const float* __restrict__ gamma,
    const float* __restrict__ beta, const float* __restrict__ Wc,
    const float* __restrict__ bc, const float* __restrict__ gfeat,
    float* __restrict__ outp)
{
    __shared__ __align__(16) char smem[40960];

    const int t = threadIdx.x;
    const int w = t >> 6, lane = t & 63;
    const int wu = __builtin_amdgcn_readfirstlane(w);
    const int wm = w & 1, wn = w >> 1;
    const int m16 = lane & 15, quad = lane >> 4;
    const int row0 = blockIdx.x * 64;

    char* const sA = smem;            // [2][4096]
    char* const sB = smem + 8192;     // [2][16384]

    const char* Ag  = A  + (size_t)(row0 + (wu & 3) * 16 + (lane >> 2)) * H_DIM + ((lane & 3) << 4);
    const char* Bg0 = Bt + (size_t)(wu * 32 + (lane >> 2)) * H_DIM + ((lane & 3) << 4);
    const char* Bg1 = Bg0 + (size_t)16 * H_DIM;

    auto stage = [&](int kt, int bi) {
        const size_t ko = (size_t)kt << 6;
        if (wu < 4) g2lds16(Ag + ko, sA + bi * 4096 + ((wu & 3) << 10));
        g2lds16(Bg0 + ko, sB + bi * 16384 + wu * 2048);
        g2lds16(Bg1 + ko, sB + bi * 16384 + wu * 2048 + 1024);
    };

    f32x4 acc[2][4];
    #pragma unroll
    for (int i = 0; i < 2; ++i)
        #pragma unroll
        for (int j = 0; j < 4; ++j)
            acc[i][j] = (f32x4){0.f, 0.f, 0.f, 0.f};

    stage(0, 0);
    #pragma unroll 1
    for (int kt = 0; kt < 16; ++kt) {
        asm volatile("s_waitcnt vmcnt(0)\n\ts_barrier" ::: "memory");
        if (kt + 1 < 16) stage(kt + 1, (kt + 1) & 1);
        const char* As = sA + (kt & 1) * 4096;
        const char* Bs = sB + (kt & 1) * 16384;
        long2v af[2], bf[4];
        #pragma unroll
        for (int i = 0; i < 2; ++i)
            af[i] = *(const long2v*)&As[(wm * 32 + i * 16 + m16) * 64 + quad * 16];
        #pragma unroll
        for (int j = 0; j < 4; ++j)
            bf[j] = *(const long2v*)&Bs[(wn * 64 + j * 16 + m16) * 64 + quad * 16];
        #pragma unroll
        for (int i = 0; i < 2; ++i)
            #pragma unroll
            for (int j = 0; j < 4; ++j) {
                acc[i][j] = __builtin_amdgcn_mfma_f32_16x16x32_fp8_fp8(
                    af[i][0], bf[j][0], acc[i][j], 0, 0, 0);
                acc[i][j] = __builtin_amdgcn_mfma_f32_16x16x32_fp8_fp8(
                    af[i][1], bf[j][1], acc[i][j], 0, 0, 0);
            }
    }
    __syncthreads();   // all LDS reads done before smem reuse

    float bj[4];
    #pragma unroll
    for (int j = 0; j < 4; ++j)
        bj[j] = bias[wn * 64 + j * 16 + m16];

    short* xs  = (short*)smem;                 // [64][264] bf16
    float* red = (float*)(smem + 33792);       // [8][64][2]
    float* mr  = (float*)(smem + 37888);       // [64][2]

    #pragma unroll
    for (int i = 0; i < 2; ++i)
        #pragma unroll
        for (int r = 0; r < 4; ++r) {
            float s = 0.f, ss = 0.f;
            #pragma unroll
            for (int j = 0; j < 4; ++j) {
                float x = acc[i][j][r] * INV_G + bj[j];
                s += x; ss += x * x;
            }
            #pragma unroll
            for (int off = 1; off <= 8; off <<= 1) {
                s  += __shfl_xor(s,  off, 64);
                ss += __shfl_xor(ss, off, 64);
            }
            if (m16 == 0) {
                const int ri = wm * 32 + i * 16 + quad * 4 + r;
                red[(w * 64 + ri) * 2 + 0] = s;
                red[(w * 64 + ri) * 2 + 1] = ss;
            }
        }
    __syncthreads();
    if (t < 64) {
        const int wmRow = t >> 5;
        float s = 0.f, ss = 0.f;
        #pragma unroll
        for (int q = 0; q < 4; ++q) {
            const int ww = wmRow + 2 * q;
            s  += red[(ww * 64 + t) * 2 + 0];
            ss += red[(ww * 64 + t) * 2 + 1];
        }
        const float mm = s * (1.f / P_DIM);
        mr[t * 2 + 0] = mm;
        mr[t * 2 + 1] = 1.f / sqrtf(fmaxf(ss * (1.f / P_DIM) - mm * mm, 0.f) + 1e-5f);
    }
    #pragma unroll
    for (int i = 0; i < 2; ++i)
        #pragma unroll
        for (int j = 0; j < 4; ++j)
            #pragma unroll
            for (int r = 0; r < 4; ++r)
                xs[(wm * 32 + i * 16 + quad * 4 + r) * 264 + wn * 64 + j * 16 + m16] =
                    f2bf(acc[i][j][r] * INV_G + bj[j]);
    __syncthreads();

    #pragma unroll 2
    for (int rr = 0; rr < 8; ++rr) {
        const int row = w * 8 + rr;
        const float mm = mr[row * 2 + 0], rs = mr[row * 2 + 1];
        const int c = lane * 4;
        short4v xv = *(const short4v*)&xs[row * 264 + c];
        float4 ga = *(const float4*)&gamma[c];
        float4 ba = *(const float4*)&beta[c];
        const float gv[4] = {ga.x, ga.y, ga.z, ga.w};
        const float bvv[4] = {ba.x, ba.y, ba.z, ba.w};
        float p[7] = {0.f, 0.f, 0.f, 0.f, 0.f, 0.f, 0.f};
        #pragma unroll
        for (int e = 0; e < 4; ++e) {
            const float yv = fmaxf((bf2f(xv[e]) - mm) * rs * gv[e] + bvv[e], 0.f);
            const float* wr = &Wc[(c + e) * 7];
            #pragma unroll
            for (int c7 = 0; c7 < 7; ++c7) p[c7] += yv * wr[c7];
        }
        #pragma unroll
        for (int off = 32; off > 0; off >>= 1)
            #pragma unroll
            for (int c7 = 0; c7 < 7; ++c7) p[c7] += __shfl_xor(p[c7], off, 64);
        if (lane == 0) {
            const size_t gr = (size_t)(row0 + row);
            int g1 = (gfeat[gr * 2 + 0] != 0.f);
            int g2 = (gfeat[gr * 2 + 1] != 0.f);
            unsigned bits = (g1 == g2) ? (g1 ? 0x24u : 0x12u) : 0x49u;
            #pragma unroll
            for (int c7 = 0; c7 < 7; ++c7)
                outp[gr * 7 + c7] = ((bits >> c7) & 1u) ? p[c7] + bc[c7] : NEG_BIG;
        }
    }
}

// ---------------------------------------------------------------------------
extern "C" void kernel_launch(void* const* d_in, const int* in_sizes, int n_in,
                              void* d_out, int out_size, void* d_ws, size_t ws_size,
                              hipStream_t stream)
{
    const float* x1   = (const float*)d_in[0];
    const float* x2   = (const float*)d_in[1];
    const float* gf   = (const float*)d_in[2];
    const float* W_in = (const float*)d_in[3];
    const float* b_in = (const float*)d_in[4];
    const float* g_in = (const float*)d_in[5];
    const float* be_in = (const float*)d_in[6];
    const float* W_r1 = (const float*)d_in[7];
    const float* b_r1 = (const float*)d_in[8];
    const float* g_r1 = (const float*)d_in[9];
    const float* be_r1 = (const float*)d_in[10];
    const float* W_r2 = (const float*)d_in[11];
    const float* b_r2 = (const float*)d_in[12];
    const float* g_r2 = (const float*)d_in[13];
    const float* be_r2 = (const float*)d_in[14];
    const float* W_f  = (const float*)d_in[15];
    const float* b_f  = (const float*)d_in[16];
    const float* g_f  = (const float*)d_in[17];
    const float* be_f = (const float*)d_in[18];
    const float* W_c  = (const float*)d_in[19];
    const float* b_c  = (const float*)d_in[20];
    float* out = (float*)d_out;

    const int B = B_ROWS;

    // ---- workspace layout (no fb buffer any more) ----
    char* p = (char*)d_ws;
    char*  A1    = p;            p += (size_t)B * K1_PAD;     // fp8, stride 1152
    char*  act   = p;            p += (size_t)B * H_DIM;      // fp8, stride 1024 (in-place)
    short* preb  = (short*)p;    p += (size_t)B * H_DIM * 2;  // bf16 GEMM out
    char*  Wt_in = p;            p += (size_t)H_DIM * K1_PAD;
    char*  Wt_r1 = p;            p += (size_t)H_DIM * H_DIM;
    char*  Wt_r2 = p;            p += (size_t)H_DIM * H_DIM;
    char*  Wt_f  = p;            p += (size_t)P_DIM * H_DIM;

    // 1) prep (single-pass L2 norm + fp8 A1) + all weight transposes
    prep_trans<<<PREP_BLKS + NTB_ALL, 256, 0, stream>>>(
        x1, x2, gf, A1,
        W_in, Wt_in, W_r1, Wt_r1, W_r2, Wt_r2, W_f, Wt_f);

    // 2) input_proj GEMM + LN1 -> act fp8
    gemm256_f8<K1_PAD><<<dim3(B / 256, H_DIM / 256), 512, 0, stream>>>(
        A1, Wt_in, b_in, INV_G1, preb, H_DIM);
    ln_relu_f8<0><<<B / 4, 256, 0, stream>>>(preb, g_in, be_in, act);

    // 3) residual block 1 (residual carried in fp8 act, in-place)
    gemm256_f8<H_DIM><<<dim3(B / 256, H_DIM / 256), 512, 0, stream>>>(
        act, Wt_r1, b_r1, INV_G, preb, H_DIM);
    ln_relu_f8<1><<<B / 4, 256, 0, stream>>>(preb, g_r1, be_r1, act);

    // 4) residual block 2
    gemm256_f8<H_DIM><<<dim3(B / 256, H_DIM / 256), 512, 0, stream>>>(
        act, Wt_r2, b_r2, INV_G, preb, H_DIM);
    ln_relu_f8<1><<<B / 4, 256, 0, stream>>>(preb, g_r2, be_r2, act);

    // 5) final_proj + final LN + classifier + gender mask (fused)
    gemm_fcls<<<B / 64, 512, 0, stream>>>(
        act, Wt_f, b_f, g_f, be_f, W_c, b_c, gf, out);
}

// Round 6
// 284.361 us; speedup vs baseline: 2.0587x; 1.0367x over previous
//
#include <hip/hip_runtime.h>
#include <cmath>

#define B_ROWS 16384
#define E_DIM 512
#define H_DIM 1024
#define P_DIM 256
#define K1_RAW 1026
#define K1_PAD 1088   // 17 x 64-K tiles (per-tile loop handles odd NK)

#define NEG_BIG (-3.0e38f)
#define SCL_IN  16.0f            // fp8 pre-scale for A1 and all weights
#define INV_G1  (1.0f / 256.0f)  // GEMM1: A(x16) * W(x16)
#define INV_G   (1.0f / 16.0f)   // GEMM2-4: A(x1) * W(x16)

typedef __attribute__((ext_vector_type(4))) short short4v;
typedef __attribute__((ext_vector_type(8))) short short8v;
typedef __attribute__((ext_vector_type(4))) float f32x4;
typedef __attribute__((ext_vector_type(2))) long long2v;

__device__ __forceinline__ short f2bf(float f) {
    unsigned u = __float_as_uint(f);
    u += 0x7fffu + ((u >> 16) & 1u);   // round-to-nearest-even
    return (short)(u >> 16);
}
__device__ __forceinline__ float bf2f(short s) {
    return __uint_as_float(((unsigned)(unsigned short)s) << 16);
}
// pack 4 floats -> 4 OCP e4m3 bytes (HW cvt, RNE+sat)
__device__ __forceinline__ int pk4_fp8(float a, float b, float c, float d) {
    int v = __builtin_amdgcn_cvt_pk_fp8_f32(a, b, 0, false);
    return  __builtin_amdgcn_cvt_pk_fp8_f32(c, d, v, true);
}

// K-interleave permutation: within each 64-k block, store the 8 eight-byte
// MFMA quad-chunks as [A0 B0 A1 B1 A2 B2 A3 B3] so one b128 read at quad*16
// returns {k-step0 frag, k-step1 frag} for mfma_16x16x32_fp8_fp8.
__device__ __forceinline__ int kperm(int k) {
    return (k & ~63) | (((k >> 3) & 3) << 4) | (((k >> 5) & 1) << 3) | (k & 7);
}

// async global->LDS DMA, 16 B/lane; lds dest = wave-uniform base + lane*16
__device__ __forceinline__ void g2lds16(const void* g, void* l) {
    __builtin_amdgcn_global_load_lds(
        (const __attribute__((address_space(1))) void*)g,
        (__attribute__((address_space(3))) void*)l, 16, 0, 0);
}

// ---------------------------------------------------------------------------
// prep_trans: blocks [0, B/4): per-row L2 norm + fp8 A1 emit, one wave per
// row (single global read). Blocks [B/4, B/4+848): weight transpose+cvt.
#define NTB_Z0 272   // 17*16
#define NTB_Z1 256
#define NTB_Z2 256
#define NTB_Z3 64
#define NTB_ALL (NTB_Z0 + NTB_Z1 + NTB_Z2 + NTB_Z3)
#define PREP_BLKS (B_ROWS / 4)

__global__ __launch_bounds__(256) void prep_trans(
    const float* __restrict__ x1, const float* __restrict__ x2,
    const float* __restrict__ gf, char* __restrict__ A1,
    const float* __restrict__ W0, char* __restrict__ Wt0,
    const float* __restrict__ W1, char* __restrict__ Wt1,
    const float* __restrict__ W2, char* __restrict__ Wt2,
    const float* __restrict__ W3, char* __restrict__ Wt3)
{
    __shared__ float T[64][68];
    const int t = threadIdx.x;
    const int bid = blockIdx.x;

    if (bid < PREP_BLKS) {
        const int lane = t & 63;
        const int row = bid * 4 + (t >> 6);
        const size_t rb8 = (size_t)row * E_DIM + lane * 8;
        float4 u0 = *(const float4*)&x1[rb8];
        float4 u1 = *(const float4*)&x1[rb8 + 4];
        float4 v0 = *(const float4*)&x2[rb8];
        float4 v1 = *(const float4*)&x2[rb8 + 4];
        float s1 = u0.x*u0.x + u0.y*u0.y + u0.z*u0.z + u0.w*u0.w
                 + u1.x*u1.x + u1.y*u1.y + u1.z*u1.z + u1.w*u1.w;
        float s2 = v0.x*v0.x + v0.y*v0.y + v0.z*v0.z + v0.w*v0.w
                 + v1.x*v1.x + v1.y*v1.y + v1.z*v1.z + v1.w*v1.w;
        #pragma unroll
        for (int off = 32; off > 0; off >>= 1) {
            s1 += __shfl_xor(s1, off, 64);
            s2 += __shfl_xor(s2, off, 64);
        }
        const float inv1 = SCL_IN / fmaxf(sqrtf(s1), 1e-12f);
        const float inv2 = SCL_IN / fmaxf(sqrtf(s2), 1e-12f);

        const size_t rb = (size_t)row * K1_PAD;
        const int k0 = lane * 8;
        *(int*)&A1[rb + kperm(k0)]           = pk4_fp8(u0.x*inv1, u0.y*inv1, u0.z*inv1, u0.w*inv1);
        *(int*)&A1[rb + kperm(k0 + 4)]       = pk4_fp8(u1.x*inv1, u1.y*inv1, u1.z*inv1, u1.w*inv1);
        *(int*)&A1[rb + kperm(512 + k0)]     = pk4_fp8(v0.x*inv2, v0.y*inv2, v0.z*inv2, v0.w*inv2);
        *(int*)&A1[rb + kperm(512 + k0 + 4)] = pk4_fp8(v1.x*inv2, v1.y*inv2, v1.z*inv2, v1.w*inv2);
        if (lane < 16) {
            const int k = 1024 + lane * 4;   // covers pad 1024..1087
            float a = 0.f, b = 0.f;
            if (k == 1024) { a = gf[(size_t)row * 2 + 0] * SCL_IN;
                             b = gf[(size_t)row * 2 + 1] * SCL_IN; }
            *(int*)&A1[rb + kperm(k)] = pk4_fp8(a, b, 0.f, 0.f);
        }
        return;
    }

    // ---- transpose body ----
    int job = bid - PREP_BLKS;
    const float* W; char* Wt; int K, N, Kpad, k0, n0;
    if (job < NTB_Z0)                 { W = W0; Wt = Wt0; K = K1_RAW; N = H_DIM; Kpad = K1_PAD; k0 = (job % 17) * 64; n0 = (job / 17) * 64; }
    else if (job < NTB_Z0 + NTB_Z1)   { int t2 = job - NTB_Z0;           W = W1; Wt = Wt1; K = H_DIM; N = H_DIM; Kpad = H_DIM; k0 = (t2 & 15) * 64; n0 = (t2 >> 4) * 64; }
    else if (job < NTB_Z0 + NTB_Z1 + NTB_Z2) { int t2 = job - NTB_Z0 - NTB_Z1; W = W2; Wt = Wt2; K = H_DIM; N = H_DIM; Kpad = H_DIM; k0 = (t2 & 15) * 64; n0 = (t2 >> 4) * 64; }
    else                              { int t2 = job - NTB_Z0 - NTB_Z1 - NTB_Z2; W = W3; Wt = Wt3; K = H_DIM; N = P_DIM; Kpad = H_DIM; k0 = (t2 & 15) * 64; n0 = (t2 >> 4) * 64; }

    const int r = t >> 4;          // 0..15
    const int c = (t & 15) << 2;   // 0..60
    #pragma unroll
    for (int rr = 0; rr < 4; ++rr) {
        int k = k0 + r + rr * 16;
        float4 v = (k < K) ? *(const float4*)&W[(size_t)k * N + n0 + c]
                           : make_float4(0.f, 0.f, 0.f, 0.f);
        v.x *= SCL_IN; v.y *= SCL_IN; v.z *= SCL_IN; v.w *= SCL_IN;
        *(float4*)&T[r + rr * 16][c] = v;
    }
    __syncthreads();
    const int n = n0 + (t >> 2);
    const int cn = t >> 2;
    const int ks = (t & 3) << 4;   // 0,16,32,48
    #pragma unroll
    for (int g = 0; g < 2; ++g) {
        int kk = ks + g * 8;
        int lo = pk4_fp8(T[kk+0][cn], T[kk+1][cn], T[kk+2][cn], T[kk+3][cn]);
        int hi = pk4_fp8(T[kk+4][cn], T[kk+5][cn], T[kk+6][cn], T[kk+7][cn]);
        int2 o = { lo, hi };
        int np = k0 + (((kk >> 3) & 3) << 4) + (((kk >> 5) & 1) << 3);
        *(int2*)&Wt[(size_t)n * Kpad + np] = o;
    }
}

// ---------------------------------------------------------------------------
// gemm256h: 256x128-tile fp8 GEMM, 2 blocks/CU (grid 512, 48KB LDS,
// VGPR<=128 via launch_bounds(512,4) -> 16 waves/CU). Per-tile K-loop with
// prefetch depth 2 and COUNTED vmcnt(3) (loads stay in flight across the
// barrier; never drained to 0 in the loop). 8 waves as 4M x 2N: wave tile
// 64x64, acc[4][4]. Per tile per thread: 3 global_load_lds (A-lo/A-hi/B).
template <int KA>
__global__ __launch_bounds__(512, 4) void gemm256h(
    const char* __restrict__ A, const char* __restrict__ Bt,
    const float* __restrict__ bias, float cscale,
    short* __restrict__ Cb, int N)
{
    constexpr int NK = KA >> 6;
    static_assert(NK >= 3, "need NK >= 3");

    __shared__ __align__(16) char smem[49152];   // 2 x (A 16KB + B 8KB)

    const int t = threadIdx.x;
    const int w = t >> 6, lane = t & 63;
    const int wu = __builtin_amdgcn_readfirstlane(w);
    const int wm = w & 3, wn = w >> 2;
    const int m16 = lane & 15, quad = lane >> 4;
    const int row0 = blockIdx.x * 256, col0 = blockIdx.y * 128;

    const char* AgLo = A  + (size_t)(row0 + wu * 16 + (lane >> 2)) * KA + ((lane & 3) << 4);
    const char* AgHi = AgLo + (size_t)128 * KA;
    const char* Bg   = Bt + (size_t)(col0 + wu * 16 + (lane >> 2)) * KA + ((lane & 3) << 4);

    auto stage = [&](int kt, int buf) {
        const size_t ko = (size_t)kt << 6;
        char* base = smem + buf * 24576;
        g2lds16(AgLo + ko, base + (wu << 10));
        g2lds16(AgHi + ko, base + 8192 + (wu << 10));
        g2lds16(Bg + ko, base + 16384 + (wu << 10));
    };

    f32x4 acc[4][4];
    #pragma unroll
    for (int i = 0; i < 4; ++i)
        #pragma unroll
        for (int j = 0; j < 4; ++j)
            acc[i][j] = (f32x4){0.f, 0.f, 0.f, 0.f};

    stage(0, 0);
    stage(1, 1);

    #pragma unroll 1
    for (int kt = 0; kt < NK; ++kt) {
        // own loads of tile kt complete (tile kt+1's 3 may remain in flight);
        // barrier ensures every wave reached that point -> tile kt resident.
        if (kt + 1 < NK) asm volatile("s_waitcnt vmcnt(3)" ::: "memory");
        else             asm volatile("s_waitcnt vmcnt(0)" ::: "memory");
        __builtin_amdgcn_s_barrier();

        const char* base = smem + (kt & 1) * 24576;
        long2v a[4], b[4];
        #pragma unroll
        for (int i = 0; i < 4; ++i)
            a[i] = *(const long2v*)&base[(wm * 64 + i * 16 + m16) * 64 + quad * 16];
        #pragma unroll
        for (int j = 0; j < 4; ++j)
            b[j] = *(const long2v*)&base[16384 + (wn * 64 + j * 16 + m16) * 64 + quad * 16];
        // frags in regs before any wave's DMA may overwrite this buffer
        asm volatile("s_waitcnt lgkmcnt(0)" ::: "memory");
        __builtin_amdgcn_s_barrier();
        if (kt + 2 < NK) stage(kt + 2, kt & 1);

        __builtin_amdgcn_s_setprio(1);
        #pragma unroll
        for (int i = 0; i < 4; ++i)
            #pragma unroll
            for (int j = 0; j < 4; ++j) {
                acc[i][j] = __builtin_amdgcn_mfma_f32_16x16x32_fp8_fp8(
                    a[i][0], b[j][0], acc[i][j], 0, 0, 0);
                acc[i][j] = __builtin_amdgcn_mfma_f32_16x16x32_fp8_fp8(
                    a[i][1], b[j][1], acc[i][j], 0, 0, 0);
            }
        __builtin_amdgcn_s_setprio(0);
    }

    // ---- staged epilogue: 2 row-halves, coalesced short8 stores ----
    float bj[4];
    #pragma unroll
    for (int j = 0; j < 4; ++j)
        bj[j] = bias[col0 + wn * 64 + j * 16 + m16];

    short* Cs = (short*)smem;   // [128][136]
    #pragma unroll
    for (int ch = 0; ch < 2; ++ch) {
        __syncthreads();
        if ((wm >> 1) == ch) {
            #pragma unroll
            for (int i = 0; i < 4; ++i) {
                const int rbase = (wm & 1) * 64 + i * 16 + quad * 4;
                #pragma unroll
                for (int j = 0; j < 4; ++j) {
                    const int cc = wn * 64 + j * 16 + m16;
                    #pragma unroll
                    for (int r = 0; r < 4; ++r)
                        Cs[(rbase + r) * 136 + cc] = f2bf(acc[i][j][r] * cscale + bj[j]);
                }
            }
        }
        __syncthreads();
        #pragma unroll
        for (int p = 0; p < 4; ++p) {
            const int idx = p * 512 + t;
            const int r = idx >> 4, c8 = idx & 15;
            short8v v = *(const short8v*)&Cs[r * 136 + c8 * 8];
            *(short8v*)&Cb[(size_t)(row0 + ch * 128 + r) * N + col0 + c8 * 8] = v;
        }
    }
}

// ---------------------------------------------------------------------------
// LN+ReLU, ONE WAVE PER ROW (4 rows/block). bf16 in, fp8(kperm) out.
// Residual carry reconstructed from the PREVIOUS fp8 act (in-place buffer).
template <int HAS_RES>
__global__ __launch_bounds__(256) void ln_relu_f8(
    const short* __restrict__ X, const float* __restrict__ gamma,
    const float* __restrict__ beta, char* __restrict__ act)
{
    const int row  = blockIdx.x * 4 + (threadIdx.x >> 6);
    const int lane = threadIdx.x & 63;
    const size_t base = (size_t)row * H_DIM;

    float y[4][4];
    float s = 0.f, ss = 0.f;
    #pragma unroll
    for (int j = 0; j < 4; ++j) {
        const int idx = j * 256 + lane * 4;
        short4v xb = *(const short4v*)&X[base + idx];
        #pragma unroll
        for (int e = 0; e < 4; ++e) {
            float xv = bf2f(xb[e]);
            y[j][e] = xv;
            s += xv; ss += xv * xv;
        }
    }
    #pragma unroll
    for (int off = 32; off > 0; off >>= 1) {
        s  += __shfl_xor(s,  off, 64);
        ss += __shfl_xor(ss, off, 64);
    }
    const float m = s * (1.f / H_DIM);
    const float var = fmaxf(ss * (1.f / H_DIM) - m * m, 0.f);
    const float r = 1.f / sqrtf(var + 1e-5f);

    #pragma unroll
    for (int j = 0; j < 4; ++j) {
        const int idx = j * 256 + lane * 4;
        float4 g  = *(const float4*)&gamma[idx];
        float4 be = *(const float4*)&beta[idx];
        float gv[4] = { g.x, g.y, g.z, g.w };
        float bv[4] = { be.x, be.y, be.z, be.w };
        #pragma unroll
        for (int e = 0; e < 4; ++e)
            y[j][e] = fmaxf((y[j][e] - m) * r * gv[e] + bv[e], 0.f);
        if constexpr (HAS_RES) {
            const int rv = *(const int*)&act[base + kperm(idx)];
            y[j][0] += __builtin_amdgcn_cvt_f32_fp8(rv, 0);
            y[j][1] += __builtin_amdgcn_cvt_f32_fp8(rv, 1);
            y[j][2] += __builtin_amdgcn_cvt_f32_fp8(rv, 2);
            y[j][3] += __builtin_amdgcn_cvt_f32_fp8(rv, 3);
        }
        *(int*)&act[base + kperm(idx)] = pk4_fp8(y[j][0], y[j][1], y[j][2], y[j][3]);
    }
}

// ---------------------------------------------------------------------------
// gemm_fcls: final_proj GEMM (64x256 tile, full N=P_DIM) + fused final LN +
// classifier + gender mask. Grid 256 x 512 thr. (Verified rounds 3/5.)
__global__ __launch_bounds__(512, 2) void gemm_fcls(
    const char* __restrict__ A, const char* __restrict__ Bt,
    const float* __restrict__ bias, const float* __restrict__ gamma,
    const float* __restrict__ beta, const float* __restrict__ Wc,
    const float* __restrict__ bc, const float* __restrict__ gfeat,
    float* __restrict__ outp)
{
    __shared__ __align__(16) char smem[40960];

    const int t = threadIdx.x;
    const int w = t >> 6, lane = t & 63;
    const int wu = __builtin_amdgcn_readfirstlane(w);
    const int wm = w & 1, wn = w >> 1;
    const int m16 = lane & 15, quad = lane >> 4;
    const int row0 = blockIdx.x * 64;

    char* const sA = smem;            // [2][4096]
    char* const sB = smem + 8192;     // [2][16384]

    const char* Ag  = A  + (size_t)(row0 + (wu & 3) * 16 + (lane >> 2)) * H_DIM + ((lane & 3) << 4);
    const char* Bg0 = Bt + (size_t)(wu * 32 + (lane >> 2)) * H_DIM + ((lane & 3) << 4);
    const char* Bg1 = Bg0 + (size_t)16 * H_DIM;

    auto stage = [&](int kt, int bi) {
        const size_t ko = (size_t)kt << 6;
        if (wu < 4) g2lds16(Ag + ko, sA + bi * 4096 + ((wu & 3) << 10));
        g2lds16(Bg0 + ko, sB + bi * 16384 + wu * 2048);
        g2lds16(Bg1 + ko, sB + bi * 16384 + wu * 2048 + 1024);
    };

    f32x4 acc[2][4];
    #pragma unroll
    for (int i = 0; i < 2; ++i)
        #pragma unroll
        for (int j = 0; j < 4; ++j)
            acc[i][j] = (f32x4){0.f, 0.f, 0.f, 0.f};

    stage(0, 0);
    #pragma unroll 1
    for (int kt = 0; kt < 16; ++kt) {
        asm volatile("s_waitcnt vmcnt(0)\n\ts_barrier" ::: "memory");
        if (kt + 1 < 16) stage(kt + 1, (kt + 1) & 1);
        const char* As = sA + (kt & 1) * 4096;
        const char* Bs = sB + (kt & 1) * 16384;
        long2v af[2], bf[4];
        #pragma unroll
        for (int i = 0; i < 2; ++i)
            af[i] = *(const long2v*)&As[(wm * 32 + i * 16 + m16) * 64 + quad * 16];
        #pragma unroll
        for (int j = 0; j < 4; ++j)
            bf[j] = *(const long2v*)&Bs[(wn * 64 + j * 16 + m16) * 64 + quad * 16];
        #pragma unroll
        for (int i = 0; i < 2; ++i)
            #pragma unroll
            for (int j = 0; j < 4; ++j) {
                acc[i][j] = __builtin_amdgcn_mfma_f32_16x16x32_fp8_fp8(
                    af[i][0], bf[j][0], acc[i][j], 0, 0, 0);
                acc[i][j] = __builtin_amdgcn_mfma_f32_16x16x32_fp8_fp8(
                    af[i][1], bf[j][1], acc[i][j], 0, 0, 0);
            }
    }
    __syncthreads();   // all LDS reads done before smem reuse

    float bj[4];
    #pragma unroll
    for (int j = 0; j < 4; ++j)
        bj[j] = bias[wn * 64 + j * 16 + m16];

    short* xs  = (short*)smem;                 // [64][264] bf16
    float* red = (float*)(smem + 33792);       // [8][64][2]
    float* mr  = (float*)(smem + 37888);       // [64][2]

    #pragma unroll
    for (int i = 0; i < 2; ++i)
        #pragma unroll
        for (int r = 0; r < 4; ++r) {
            float s = 0.f, ss = 0.f;
            #pragma unroll
            for (int j = 0; j < 4; ++j) {
                float x = acc[i][j][r] * INV_G + bj[j];
                s += x; ss += x * x;
            }
            #pragma unroll
            for (int off = 1; off <= 8; off <<= 1) {
                s  += __shfl_xor(s,  off, 64);
                ss += __shfl_xor(ss, off, 64);
            }
            if (m16 == 0) {
                const int ri = wm * 32 + i * 16 + quad * 4 + r;
                red[(w * 64 + ri) * 2 + 0] = s;
                red[(w * 64 + ri) * 2 + 1] = ss;
            }
        }
    __syncthreads();
    if (t < 64) {
        const int wmRow = t >> 5;
        float s = 0.f, ss = 0.f;
        #pragma unroll
        for (int q = 0; q < 4; ++q) {
            const int ww = wmRow + 2 * q;
            s  += red[(ww * 64 + t) * 2 + 0];
            ss += red[(ww * 64 + t) * 2 + 1];
        }
        const float mm = s * (1.f / P_DIM);
        mr[t * 2 + 0] = mm;
        mr[t * 2 + 1] = 1.f / sqrtf(fmaxf(ss * (1.f / P_DIM) - mm * mm, 0.f) + 1e-5f);
    }
    #pragma unroll
    for (int i = 0; i < 2; ++i)
        #pragma unroll
        for (int j = 0; j < 4; ++j)
            #pragma unroll
            for (int r = 0; r < 4; ++r)
                xs[(wm * 32 + i * 16 + quad * 4 + r) * 264 + wn * 64 + j * 16 + m16] =
                    f2bf(acc[i][j][r] * INV_G + bj[j]);
    __syncthreads();

    #pragma unroll 2
    for (int rr = 0; rr < 8; ++rr) {
        const int row = w * 8 + rr;
        const float mm = mr[row * 2 + 0], rs = mr[row * 2 + 1];
        const int c = lane * 4;
        short4v xv = *(const short4v*)&xs[row * 264 + c];
        float4 ga = *(const float4*)&gamma[c];
        float4 ba = *(const float4*)&beta[c];
        const float gv[4] = {ga.x, ga.y, ga.z, ga.w};
        const float bvv[4] = {ba.x, ba.y, ba.z, ba.w};
        float p[7] = {0.f, 0.f, 0.f, 0.f, 0.f, 0.f, 0.f};
        #pragma unroll
        for (int e = 0; e < 4; ++e) {
            const float yv = fmaxf((bf2f(xv[e]) - mm) * rs * gv[e] + bvv[e], 0.f);
            const float* wr = &Wc[(c + e) * 7];
            #pragma unroll
            for (int c7 = 0; c7 < 7; ++c7) p[c7] += yv * wr[c7];
        }
        #pragma unroll
        for (int off = 32; off > 0; off >>= 1)
            #pragma unroll
            for (int c7 = 0; c7 < 7; ++c7) p[c7] += __shfl_xor(p[c7], off, 64);
        if (lane == 0) {
            const size_t gr = (size_t)(row0 + row);
            int g1 = (gfeat[gr * 2 + 0] != 0.f);
            int g2 = (gfeat[gr * 2 + 1] != 0.f);
            unsigned bits = (g1 == g2) ? (g1 ? 0x24u : 0x12u) : 0x49u;
            #pragma unroll
            for (int c7 = 0; c7 < 7; ++c7)
                outp[gr * 7 + c7] = ((bits >> c7) & 1u) ? p[c7] + bc[c7] : NEG_BIG;
        }
    }
}

// ---------------------------------------------------------------------------
extern "C" void kernel_launch(void* const* d_in, const int* in_sizes, int n_in,
                              void* d_out, int out_size, void* d_ws, size_t ws_size,
                              hipStream_t stream)
{
    const float* x1   = (const float*)d_in[0];
    const float* x2   = (const float*)d_in[1];
    const float* gf   = (const float*)d_in[2];
    const float* W_in = (const float*)d_in[3];
    const float* b_in = (const float*)d_in[4];
    const float* g_in = (const float*)d_in[5];
    const float* be_in = (const float*)d_in[6];
    const float* W_r1 = (const float*)d_in[7];
    const float* b_r1 = (const float*)d_in[8];
    const float* g_r1 = (const float*)d_in[9];
    const float* be_r1 = (const float*)d_in[10];
    const float* W_r2 = (const float*)d_in[11];
    const float* b_r2 = (const float*)d_in[12];
    const float* g_r2 = (const float*)d_in[13];
    const float* be_r2 = (const float*)d_in[14];
    const float* W_f  = (const float*)d_in[15];
    const float* b_f  = (const float*)d_in[16];
    const float* g_f  = (const float*)d_in[17];
    const float* be_f = (const float*)d_in[18];
    const float* W_c  = (const float*)d_in[19];
    const float* b_c  = (const float*)d_in[20];
    float* out = (float*)d_out;

    const int B = B_ROWS;

    // ---- workspace layout ----
    char* p = (char*)d_ws;
    char*  A1    = p;            p += (size_t)B * K1_PAD;     // fp8, stride 1088
    char*  act   = p;            p += (size_t)B * H_DIM;      // fp8, stride 1024 (in-place)
    short* preb  = (short*)p;    p += (size_t)B * H_DIM * 2;  // bf16 GEMM out
    char*  Wt_in = p;            p += (size_t)H_DIM * K1_PAD;
    char*  Wt_r1 = p;            p += (size_t)H_DIM * H_DIM;
    char*  Wt_r2 = p;            p += (size_t)H_DIM * H_DIM;
    char*  Wt_f  = p;            p += (size_t)P_DIM * H_DIM;

    // 1) prep (single-pass L2 norm + fp8 A1) + all weight transposes
    prep_trans<<<PREP_BLKS + NTB_ALL, 256, 0, stream>>>(
        x1, x2, gf, A1,
        W_in, Wt_in, W_r1, Wt_r1, W_r2, Wt_r2, W_f, Wt_f);

    // 2) input_proj GEMM + LN1 -> act fp8
    gemm256h<K1_PAD><<<dim3(B / 256, H_DIM / 128), 512, 0, stream>>>(
        A1, Wt_in, b_in, INV_G1, preb, H_DIM);
    ln_relu_f8<0><<<B / 4, 256, 0, stream>>>(preb, g_in, be_in, act);

    // 3) residual block 1 (residual carried in fp8 act, in-place)
    gemm256h<H_DIM><<<dim3(B / 256, H_DIM / 128), 512, 0, stream>>>(
        act, Wt_r1, b_r1, INV_G, preb, H_DIM);
    ln_relu_f8<1><<<B / 4, 256, 0, stream>>>(preb, g_r1, be_r1, act);

    // 4) residual block 2
    gemm256h<H_DIM><<<dim3(B / 256, H_DIM / 128), 512, 0, stream>>>(
        act, Wt_r2, b_r2, INV_G, preb, H_DIM);
    ln_relu_f8<1><<<B / 4, 256, 0, stream>>>(preb, g_r2, be_r2, act);

    // 5) final_proj + final LN + classifier + gender mask (fused)
    gemm_fcls<<<B / 64, 512, 0, stream>>>(
        act, Wt_f, b_f, g_f, be_f, W_c, b_c, gf, out);
}

// Round 7
// 277.894 us; speedup vs baseline: 2.1067x; 1.0233x over previous
//
#include <hip/hip_runtime.h>
#include <cmath>

#define B_ROWS 16384
#define E_DIM 512
#define H_DIM 1024
#define P_DIM 256
#define K1_RAW 1026
#define K1_PAD 1088   // 17 x 64-K tiles (per-tile loop handles odd NK)

#define NEG_BIG (-3.0e38f)
#define SCL_IN  16.0f            // fp8 pre-scale for A1 and all weights
#define INV_G1  (1.0f / 256.0f)  // GEMM1: A(x16) * W(x16)
#define INV_G   (1.0f / 16.0f)   // GEMM2-4: A(x1) * W(x16)

typedef __attribute__((ext_vector_type(4))) short short4v;
typedef __attribute__((ext_vector_type(8))) short short8v;
typedef __attribute__((ext_vector_type(4))) float f32x4;
typedef __attribute__((ext_vector_type(2))) long long2v;

__device__ __forceinline__ short f2bf(float f) {
    unsigned u = __float_as_uint(f);
    u += 0x7fffu + ((u >> 16) & 1u);   // round-to-nearest-even
    return (short)(u >> 16);
}
__device__ __forceinline__ float bf2f(short s) {
    return __uint_as_float(((unsigned)(unsigned short)s) << 16);
}
// pack 4 floats -> 4 OCP e4m3 bytes (HW cvt, RNE+sat)
__device__ __forceinline__ int pk4_fp8(float a, float b, float c, float d) {
    int v = __builtin_amdgcn_cvt_pk_fp8_f32(a, b, 0, false);
    return  __builtin_amdgcn_cvt_pk_fp8_f32(c, d, v, true);
}

// K-interleave permutation: within each 64-k block, store the 8 eight-byte
// MFMA quad-chunks as [A0 B0 A1 B1 A2 B2 A3 B3] so one b128 read at quad*16
// returns {k-step0 frag, k-step1 frag} for mfma_16x16x32_fp8_fp8.
__device__ __forceinline__ int kperm(int k) {
    return (k & ~63) | (((k >> 3) & 3) << 4) | (((k >> 5) & 1) << 3) | (k & 7);
}

// async global->LDS DMA, 16 B/lane; lds dest = wave-uniform base + lane*16
__device__ __forceinline__ void g2lds16(const void* g, void* l) {
    __builtin_amdgcn_global_load_lds(
        (const __attribute__((address_space(1))) void*)g,
        (__attribute__((address_space(3))) void*)l, 16, 0, 0);
}

// ---------------------------------------------------------------------------
// prep_trans: blocks [0, B/4): per-row L2 norm + fp8 A1 emit, one wave per
// row (single global read). Blocks [B/4, B/4+848): weight transpose+cvt.
#define NTB_Z0 272   // 17*16
#define NTB_Z1 256
#define NTB_Z2 256
#define NTB_Z3 64
#define NTB_ALL (NTB_Z0 + NTB_Z1 + NTB_Z2 + NTB_Z3)
#define PREP_BLKS (B_ROWS / 4)

__global__ __launch_bounds__(256) void prep_trans(
    const float* __restrict__ x1, const float* __restrict__ x2,
    const float* __restrict__ gf, char* __restrict__ A1,
    const float* __restrict__ W0, char* __restrict__ Wt0,
    const float* __restrict__ W1, char* __restrict__ Wt1,
    const float* __restrict__ W2, char* __restrict__ Wt2,
    const float* __restrict__ W3, char* __restrict__ Wt3)
{
    __shared__ float T[64][68];
    const int t = threadIdx.x;
    const int bid = blockIdx.x;

    if (bid < PREP_BLKS) {
        const int lane = t & 63;
        const int row = bid * 4 + (t >> 6);
        const size_t rb8 = (size_t)row * E_DIM + lane * 8;
        float4 u0 = *(const float4*)&x1[rb8];
        float4 u1 = *(const float4*)&x1[rb8 + 4];
        float4 v0 = *(const float4*)&x2[rb8];
        float4 v1 = *(const float4*)&x2[rb8 + 4];
        float s1 = u0.x*u0.x + u0.y*u0.y + u0.z*u0.z + u0.w*u0.w
                 + u1.x*u1.x + u1.y*u1.y + u1.z*u1.z + u1.w*u1.w;
        float s2 = v0.x*v0.x + v0.y*v0.y + v0.z*v0.z + v0.w*v0.w
                 + v1.x*v1.x + v1.y*v1.y + v1.z*v1.z + v1.w*v1.w;
        #pragma unroll
        for (int off = 32; off > 0; off >>= 1) {
            s1 += __shfl_xor(s1, off, 64);
            s2 += __shfl_xor(s2, off, 64);
        }
        const float inv1 = SCL_IN / fmaxf(sqrtf(s1), 1e-12f);
        const float inv2 = SCL_IN / fmaxf(sqrtf(s2), 1e-12f);

        const size_t rb = (size_t)row * K1_PAD;
        const int k0 = lane * 8;
        *(int*)&A1[rb + kperm(k0)]           = pk4_fp8(u0.x*inv1, u0.y*inv1, u0.z*inv1, u0.w*inv1);
        *(int*)&A1[rb + kperm(k0 + 4)]       = pk4_fp8(u1.x*inv1, u1.y*inv1, u1.z*inv1, u1.w*inv1);
        *(int*)&A1[rb + kperm(512 + k0)]     = pk4_fp8(v0.x*inv2, v0.y*inv2, v0.z*inv2, v0.w*inv2);
        *(int*)&A1[rb + kperm(512 + k0 + 4)] = pk4_fp8(v1.x*inv2, v1.y*inv2, v1.z*inv2, v1.w*inv2);
        if (lane < 16) {
            const int k = 1024 + lane * 4;   // covers pad 1024..1087
            float a = 0.f, b = 0.f;
            if (k == 1024) { a = gf[(size_t)row * 2 + 0] * SCL_IN;
                             b = gf[(size_t)row * 2 + 1] * SCL_IN; }
            *(int*)&A1[rb + kperm(k)] = pk4_fp8(a, b, 0.f, 0.f);
        }
        return;
    }

    // ---- transpose body ----
    int job = bid - PREP_BLKS;
    const float* W; char* Wt; int K, N, Kpad, k0, n0;
    if (job < NTB_Z0)                 { W = W0; Wt = Wt0; K = K1_RAW; N = H_DIM; Kpad = K1_PAD; k0 = (job % 17) * 64; n0 = (job / 17) * 64; }
    else if (job < NTB_Z0 + NTB_Z1)   { int t2 = job - NTB_Z0;           W = W1; Wt = Wt1; K = H_DIM; N = H_DIM; Kpad = H_DIM; k0 = (t2 & 15) * 64; n0 = (t2 >> 4) * 64; }
    else if (job < NTB_Z0 + NTB_Z1 + NTB_Z2) { int t2 = job - NTB_Z0 - NTB_Z1; W = W2; Wt = Wt2; K = H_DIM; N = H_DIM; Kpad = H_DIM; k0 = (t2 & 15) * 64; n0 = (t2 >> 4) * 64; }
    else                              { int t2 = job - NTB_Z0 - NTB_Z1 - NTB_Z2; W = W3; Wt = Wt3; K = H_DIM; N = P_DIM; Kpad = H_DIM; k0 = (t2 & 15) * 64; n0 = (t2 >> 4) * 64; }

    const int r = t >> 4;          // 0..15
    const int c = (t & 15) << 2;   // 0..60
    #pragma unroll
    for (int rr = 0; rr < 4; ++rr) {
        int k = k0 + r + rr * 16;
        float4 v = (k < K) ? *(const float4*)&W[(size_t)k * N + n0 + c]
                           : make_float4(0.f, 0.f, 0.f, 0.f);
        v.x *= SCL_IN; v.y *= SCL_IN; v.z *= SCL_IN; v.w *= SCL_IN;
        *(float4*)&T[r + rr * 16][c] = v;
    }
    __syncthreads();
    const int n = n0 + (t >> 2);
    const int cn = t >> 2;
    const int ks = (t & 3) << 4;   // 0,16,32,48
    #pragma unroll
    for (int g = 0; g < 2; ++g) {
        int kk = ks + g * 8;
        int lo = pk4_fp8(T[kk+0][cn], T[kk+1][cn], T[kk+2][cn], T[kk+3][cn]);
        int hi = pk4_fp8(T[kk+4][cn], T[kk+5][cn], T[kk+6][cn], T[kk+7][cn]);
        int2 o = { lo, hi };
        int np = k0 + (((kk >> 3) & 3) << 4) + (((kk >> 5) & 1) << 3);
        *(int2*)&Wt[(size_t)n * Kpad + np] = o;
    }
}

// ---------------------------------------------------------------------------
// gemm256h: 256x128-tile fp8 GEMM, 2 blocks/CU, TRIPLE-buffered LDS (72KB).
// ONE barrier per 64-K tile: stage(kt+2) writes buf[(kt+2)%3], whose last
// readers finished at tile kt-1 (their ds_read data was consumed into regs
// before they arrived at barrier(kt)) -> no mid-loop lgkm drain needed.
// Counted vmcnt(3): tile kt+1's 3 loads stay in flight across the barrier.
template <int KA>
__global__ __launch_bounds__(512, 4) void gemm256h(
    const char* __restrict__ A, const char* __restrict__ Bt,
    const float* __restrict__ bias, float cscale,
    short* __restrict__ Cb, int N)
{
    constexpr int NK = KA >> 6;
    static_assert(NK >= 3, "need NK >= 3");

    __shared__ __align__(16) char smem[73728];   // 3 x (A 16KB + B 8KB)

    const int t = threadIdx.x;
    const int w = t >> 6, lane = t & 63;
    const int wu = __builtin_amdgcn_readfirstlane(w);
    const int wm = w & 3, wn = w >> 2;
    const int m16 = lane & 15, quad = lane >> 4;
    const int row0 = blockIdx.x * 256, col0 = blockIdx.y * 128;

    const char* AgLo = A  + (size_t)(row0 + wu * 16 + (lane >> 2)) * KA + ((lane & 3) << 4);
    const char* AgHi = AgLo + (size_t)128 * KA;
    const char* Bg   = Bt + (size_t)(col0 + wu * 16 + (lane >> 2)) * KA + ((lane & 3) << 4);

    auto stage = [&](int kt, int buf) {
        const size_t ko = (size_t)kt << 6;
        char* base = smem + buf * 24576;
        g2lds16(AgLo + ko, base + (wu << 10));
        g2lds16(AgHi + ko, base + 8192 + (wu << 10));
        g2lds16(Bg + ko, base + 16384 + (wu << 10));
    };

    f32x4 acc[4][4];
    #pragma unroll
    for (int i = 0; i < 4; ++i)
        #pragma unroll
        for (int j = 0; j < 4; ++j)
            acc[i][j] = (f32x4){0.f, 0.f, 0.f, 0.f};

    stage(0, 0);
    stage(1, 1);
    int bufr = 0, bufs = 2;

    #pragma unroll 1
    for (int kt = 0; kt < NK; ++kt) {
        // tile kt's 3 own loads complete; tile kt+1's 3 may stay in flight.
        if (kt + 1 < NK) asm volatile("s_waitcnt vmcnt(3)" ::: "memory");
        else             asm volatile("s_waitcnt vmcnt(0)" ::: "memory");
        __builtin_amdgcn_s_barrier();

        const char* base = smem + bufr * 24576;
        bufr = (bufr == 2) ? 0 : bufr + 1;
        long2v a[4], b[4];
        #pragma unroll
        for (int i = 0; i < 4; ++i)
            a[i] = *(const long2v*)&base[(wm * 64 + i * 16 + m16) * 64 + quad * 16];
        #pragma unroll
        for (int j = 0; j < 4; ++j)
            b[j] = *(const long2v*)&base[16384 + (wn * 64 + j * 16 + m16) * 64 + quad * 16];

        if (kt + 2 < NK) {
            stage(kt + 2, bufs);
            bufs = (bufs == 2) ? 0 : bufs + 1;
        }

        __builtin_amdgcn_s_setprio(1);
        #pragma unroll
        for (int i = 0; i < 4; ++i)
            #pragma unroll
            for (int j = 0; j < 4; ++j) {
                acc[i][j] = __builtin_amdgcn_mfma_f32_16x16x32_fp8_fp8(
                    a[i][0], b[j][0], acc[i][j], 0, 0, 0);
                acc[i][j] = __builtin_amdgcn_mfma_f32_16x16x32_fp8_fp8(
                    a[i][1], b[j][1], acc[i][j], 0, 0, 0);
            }
        __builtin_amdgcn_s_setprio(0);
    }

    // ---- staged epilogue: 2 row-halves, coalesced short8 stores ----
    float bj[4];
    #pragma unroll
    for (int j = 0; j < 4; ++j)
        bj[j] = bias[col0 + wn * 64 + j * 16 + m16];

    short* Cs = (short*)smem;   // [128][136]
    #pragma unroll
    for (int ch = 0; ch < 2; ++ch) {
        __syncthreads();
        if ((wm >> 1) == ch) {
            #pragma unroll
            for (int i = 0; i < 4; ++i) {
                const int rbase = (wm & 1) * 64 + i * 16 + quad * 4;
                #pragma unroll
                for (int j = 0; j < 4; ++j) {
                    const int cc = wn * 64 + j * 16 + m16;
                    #pragma unroll
                    for (int r = 0; r < 4; ++r)
                        Cs[(rbase + r) * 136 + cc] = f2bf(acc[i][j][r] * cscale + bj[j]);
                }
            }
        }
        __syncthreads();
        #pragma unroll
        for (int p = 0; p < 4; ++p) {
            const int idx = p * 512 + t;
            const int r = idx >> 4, c8 = idx & 15;
            short8v v = *(const short8v*)&Cs[r * 136 + c8 * 8];
            *(short8v*)&Cb[(size_t)(row0 + ch * 128 + r) * N + col0 + c8 * 8] = v;
        }
    }
}

// ---------------------------------------------------------------------------
// LN+ReLU, ONE WAVE PER ROW (4 rows/block). bf16 in, fp8(kperm) out.
// Residual carry reconstructed from the PREVIOUS fp8 act (in-place buffer).
template <int HAS_RES>
__global__ __launch_bounds__(256) void ln_relu_f8(
    const short* __restrict__ X, const float* __restrict__ gamma,
    const float* __restrict__ beta, char* __restrict__ act)
{
    const int row  = blockIdx.x * 4 + (threadIdx.x >> 6);
    const int lane = threadIdx.x & 63;
    const size_t base = (size_t)row * H_DIM;

    float y[4][4];
    float s = 0.f, ss = 0.f;
    #pragma unroll
    for (int j = 0; j < 4; ++j) {
        const int idx = j * 256 + lane * 4;
        short4v xb = *(const short4v*)&X[base + idx];
        #pragma unroll
        for (int e = 0; e < 4; ++e) {
            float xv = bf2f(xb[e]);
            y[j][e] = xv;
            s += xv; ss += xv * xv;
        }
    }
    #pragma unroll
    for (int off = 32; off > 0; off >>= 1) {
        s  += __shfl_xor(s,  off, 64);
        ss += __shfl_xor(ss, off, 64);
    }
    const float m = s * (1.f / H_DIM);
    const float var = fmaxf(ss * (1.f / H_DIM) - m * m, 0.f);
    const float r = 1.f / sqrtf(var + 1e-5f);

    #pragma unroll
    for (int j = 0; j < 4; ++j) {
        const int idx = j * 256 + lane * 4;
        float4 g  = *(const float4*)&gamma[idx];
        float4 be = *(const float4*)&beta[idx];
        float gv[4] = { g.x, g.y, g.z, g.w };
        float bv[4] = { be.x, be.y, be.z, be.w };
        #pragma unroll
        for (int e = 0; e < 4; ++e)
            y[j][e] = fmaxf((y[j][e] - m) * r * gv[e] + bv[e], 0.f);
        if constexpr (HAS_RES) {
            const int rv = *(const int*)&act[base + kperm(idx)];
            y[j][0] += __builtin_amdgcn_cvt_f32_fp8(rv, 0);
            y[j][1] += __builtin_amdgcn_cvt_f32_fp8(rv, 1);
            y[j][2] += __builtin_amdgcn_cvt_f32_fp8(rv, 2);
            y[j][3] += __builtin_amdgcn_cvt_f32_fp8(rv, 3);
        }
        *(int*)&act[base + kperm(idx)] = pk4_fp8(y[j][0], y[j][1], y[j][2], y[j][3]);
    }
}

// ---------------------------------------------------------------------------
// gemm_fcls: final_proj GEMM (64x256 tile, full N=P_DIM) + fused final LN +
// classifier + gender mask. Triple-buffered A+B staging, counted vmcnt(2)
// (conservative bound: waves stage 2 or 3 chunks/tile). ONE barrier/tile.
__global__ __launch_bounds__(512, 2) void gemm_fcls(
    const char* __restrict__ A, const char* __restrict__ Bt,
    const float* __restrict__ bias, const float* __restrict__ gamma,
    const float* __restrict__ beta, const float* __restrict__ Wc,
    const float* __restrict__ bc, const float* __restrict__ gfeat,
    float* __restrict__ outp)
{
    __shared__ __align__(16) char smem[61440];   // 3 x (A 4KB + B 16KB)

    const int t = threadIdx.x;
    const int w = t >> 6, lane = t & 63;
    const int wu = __builtin_amdgcn_readfirstlane(w);
    const int wm = w & 1, wn = w >> 1;
    const int m16 = lane & 15, quad = lane >> 4;
    const int row0 = blockIdx.x * 64;

    const char* Ag  = A  + (size_t)(row0 + (wu & 3) * 16 + (lane >> 2)) * H_DIM + ((lane & 3) << 4);
    const char* Bg0 = Bt + (size_t)(wu * 32 + (lane >> 2)) * H_DIM + ((lane & 3) << 4);
    const char* Bg1 = Bg0 + (size_t)16 * H_DIM;

    auto stage = [&](int kt, int buf) {
        const size_t ko = (size_t)kt << 6;
        char* base = smem + buf * 20480;
        if (wu < 4) g2lds16(Ag + ko, base + ((wu & 3) << 10));
        g2lds16(Bg0 + ko, base + 4096 + wu * 2048);
        g2lds16(Bg1 + ko, base + 4096 + wu * 2048 + 1024);
    };

    f32x4 acc[2][4];
    #pragma unroll
    for (int i = 0; i < 2; ++i)
        #pragma unroll
        for (int j = 0; j < 4; ++j)
            acc[i][j] = (f32x4){0.f, 0.f, 0.f, 0.f};

    stage(0, 0);
    stage(1, 1);
    int bufr = 0, bufs = 2;

    #pragma unroll 1
    for (int kt = 0; kt < 16; ++kt) {
        if (kt + 1 < 16) asm volatile("s_waitcnt vmcnt(2)" ::: "memory");
        else             asm volatile("s_waitcnt vmcnt(0)" ::: "memory");
        __builtin_amdgcn_s_barrier();

        const char* As = smem + bufr * 20480;
        const char* Bs = As + 4096;
        bufr = (bufr == 2) ? 0 : bufr + 1;
        long2v af[2], bf[4];
        #pragma unroll
        for (int i = 0; i < 2; ++i)
            af[i] = *(const long2v*)&As[(wm * 32 + i * 16 + m16) * 64 + quad * 16];
        #pragma unroll
        for (int j = 0; j < 4; ++j)
            bf[j] = *(const long2v*)&Bs[(wn * 64 + j * 16 + m16) * 64 + quad * 16];

        if (kt + 2 < 16) {
            stage(kt + 2, bufs);
            bufs = (bufs == 2) ? 0 : bufs + 1;
        }

        __builtin_amdgcn_s_setprio(1);
        #pragma unroll
        for (int i = 0; i < 2; ++i)
            #pragma unroll
            for (int j = 0; j < 4; ++j) {
                acc[i][j] = __builtin_amdgcn_mfma_f32_16x16x32_fp8_fp8(
                    af[i][0], bf[j][0], acc[i][j], 0, 0, 0);
                acc[i][j] = __builtin_amdgcn_mfma_f32_16x16x32_fp8_fp8(
                    af[i][1], bf[j][1], acc[i][j], 0, 0, 0);
            }
        __builtin_amdgcn_s_setprio(0);
    }
    __syncthreads();   // all LDS reads done before smem reuse

    float bj[4];
    #pragma unroll
    for (int j = 0; j < 4; ++j)
        bj[j] = bias[wn * 64 + j * 16 + m16];

    short* xs  = (short*)smem;                 // [64][264] bf16
    float* red = (float*)(smem + 33792);       // [8][64][2]
    float* mr  = (float*)(smem + 37888);       // [64][2]

    #pragma unroll
    for (int i = 0; i < 2; ++i)
        #pragma unroll
        for (int r = 0; r < 4; ++r) {
            float s = 0.f, ss = 0.f;
            #pragma unroll
            for (int j = 0; j < 4; ++j) {
                float x = acc[i][j][r] * INV_G + bj[j];
                s += x; ss += x * x;
            }
            #pragma unroll
            for (int off = 1; off <= 8; off <<= 1) {
                s  += __shfl_xor(s,  off, 64);
                ss += __shfl_xor(ss, off, 64);
            }
            if (m16 == 0) {
                const int ri = wm * 32 + i * 16 + quad * 4 + r;
                red[(w * 64 + ri) * 2 + 0] = s;
                red[(w * 64 + ri) * 2 + 1] = ss;
            }
        }
    __syncthreads();
    if (t < 64) {
        const int wmRow = t >> 5;
        float s = 0.f, ss = 0.f;
        #pragma unroll
        for (int q = 0; q < 4; ++q) {
            const int ww = wmRow + 2 * q;
            s  += red[(ww * 64 + t) * 2 + 0];
            ss += red[(ww * 64 + t) * 2 + 1];
        }
        const float mm = s * (1.f / P_DIM);
        mr[t * 2 + 0] = mm;
        mr[t * 2 + 1] = 1.f / sqrtf(fmaxf(ss * (1.f / P_DIM) - mm * mm, 0.f) + 1e-5f);
    }
    #pragma unroll
    for (int i = 0; i < 2; ++i)
        #pragma unroll
        for (int j = 0; j < 4; ++j)
            #pragma unroll
            for (int r = 0; r < 4; ++r)
                xs[(wm * 32 + i * 16 + quad * 4 + r) * 264 + wn * 64 + j * 16 + m16] =
                    f2bf(acc[i][j][r] * INV_G + bj[j]);
    __syncthreads();

    #pragma unroll 2
    for (int rr = 0; rr < 8; ++rr) {
        const int row = w * 8 + rr;
        const float mm = mr[row * 2 + 0], rs = mr[row * 2 + 1];
        const int c = lane * 4;
        short4v xv = *(const short4v*)&xs[row * 264 + c];
        float4 ga = *(const float4*)&gamma[c];
        float4 ba = *(const float4*)&beta[c];
        const float gv[4] = {ga.x, ga.y, ga.z, ga.w};
        const float bvv[4] = {ba.x, ba.y, ba.z, ba.w};
        float p[7] = {0.f, 0.f, 0.f, 0.f, 0.f, 0.f, 0.f};
        #pragma unroll
        for (int e = 0; e < 4; ++e) {
            const float yv = fmaxf((bf2f(xv[e]) - mm) * rs * gv[e] + bvv[e], 0.f);
            const float* wr = &Wc[(c + e) * 7];
            #pragma unroll
            for (int c7 = 0; c7 < 7; ++c7) p[c7] += yv * wr[c7];
        }
        #pragma unroll
        for (int off = 32; off > 0; off >>= 1)
            #pragma unroll
            for (int c7 = 0; c7 < 7; ++c7) p[c7] += __shfl_xor(p[c7], off, 64);
        if (lane == 0) {
            const size_t gr = (size_t)(row0 + row);
            int g1 = (gfeat[gr * 2 + 0] != 0.f);
            int g2 = (gfeat[gr * 2 + 1] != 0.f);
            unsigned bits = (g1 == g2) ? (g1 ? 0x24u : 0x12u) : 0x49u;
            #pragma unroll
            for (int c7 = 0; c7 < 7; ++c7)
                outp[gr * 7 + c7] = ((bits >> c7) & 1u) ? p[c7] + bc[c7] : NEG_BIG;
        }
    }
}

// ---------------------------------------------------------------------------
extern "C" void kernel_launch(void* const* d_in, const int* in_sizes, int n_in,
                              void* d_out, int out_size, void* d_ws, size_t ws_size,
                              hipStream_t stream)
{
    const float* x1   = (const float*)d_in[0];
    const float* x2   = (const float*)d_in[1];
    const float* gf   = (const float*)d_in[2];
    const float* W_in = (const float*)d_in[3];
    const float* b_in = (const float*)d_in[4];
    const float* g_in = (const float*)d_in[5];
    const float* be_in = (const float*)d_in[6];
    const float* W_r1 = (const float*)d_in[7];
    const float* b_r1 = (const float*)d_in[8];
    const float* g_r1 = (const float*)d_in[9];
    const float* be_r1 = (const float*)d_in[10];
    const float* W_r2 = (const float*)d_in[11];
    const float* b_r2 = (const float*)d_in[12];
    const float* g_r2 = (const float*)d_in[13];
    const float* be_r2 = (const float*)d_in[14];
    const float* W_f  = (const float*)d_in[15];
    const float* b_f  = (const float*)d_in[16];
    const float* g_f  = (const float*)d_in[17];
    const float* be_f = (const float*)d_in[18];
    const float* W_c  = (const float*)d_in[19];
    const float* b_c  = (const float*)d_in[20];
    float* out = (float*)d_out;

    const int B = B_ROWS;

    // ---- workspace layout ----
    char* p = (char*)d_ws;
    char*  A1    = p;            p += (size_t)B * K1_PAD;     // fp8, stride 1088
    char*  act   = p;            p += (size_t)B * H_DIM;      // fp8, stride 1024 (in-place)
    short* preb  = (short*)p;    p += (size_t)B * H_DIM * 2;  // bf16 GEMM out
    char*  Wt_in = p;            p += (size_t)H_DIM * K1_PAD;
    char*  Wt_r1 = p;            p += (size_t)H_DIM * H_DIM;
    char*  Wt_r2 = p;            p += (size_t)H_DIM * H_DIM;
    char*  Wt_f  = p;            p += (size_t)P_DIM * H_DIM;

    // 1) prep (single-pass L2 norm + fp8 A1) + all weight transposes
    prep_trans<<<PREP_BLKS + NTB_ALL, 256, 0, stream>>>(
        x1, x2, gf, A1,
        W_in, Wt_in, W_r1, Wt_r1, W_r2, Wt_r2, W_f, Wt_f);

    // 2) input_proj GEMM + LN1 -> act fp8
    gemm256h<K1_PAD><<<dim3(B / 256, H_DIM / 128), 512, 0, stream>>>(
        A1, Wt_in, b_in, INV_G1, preb, H_DIM);
    ln_relu_f8<0><<<B / 4, 256, 0, stream>>>(preb, g_in, be_in, act);

    // 3) residual block 1 (residual carried in fp8 act, in-place)
    gemm256h<H_DIM><<<dim3(B / 256, H_DIM / 128), 512, 0, stream>>>(
        act, Wt_r1, b_r1, INV_G, preb, H_DIM);
    ln_relu_f8<1><<<B / 4, 256, 0, stream>>>(preb, g_r1, be_r1, act);

    // 4) residual block 2
    gemm256h<H_DIM><<<dim3(B / 256, H_DIM / 128), 512, 0, stream>>>(
        act, Wt_r2, b_r2, INV_G, preb, H_DIM);
    ln_relu_f8<1><<<B / 4, 256, 0, stream>>>(preb, g_r2, be_r2, act);

    // 5) final_proj + final LN + classifier + gender mask (fused)
    gemm_fcls<<<B / 64, 512, 0, stream>>>(
        act, Wt_f, b_f, g_f, be_f, W_c, b_c, gf, out);
}

// Round 8
// 275.020 us; speedup vs baseline: 2.1287x; 1.0104x over previous
//
#include <hip/hip_runtime.h>
#include <cmath>

#define B_ROWS 16384
#define E_DIM 512
#define H_DIM 1024
#define P_DIM 256
#define K1_RAW 1026
#define K1_PAD 1088   // 17 x 64-K tiles (per-tile loop handles odd NK)

#define NEG_BIG (-3.0e38f)
#define SCL_IN  16.0f            // fp8 pre-scale for A1 and all weights
#define INV_G1  (1.0f / 256.0f)  // GEMM1: A(x16) * W(x16)
#define INV_G   (1.0f / 16.0f)   // GEMM2-4: A(x1) * W(x16)

typedef __attribute__((ext_vector_type(4))) short short4v;
typedef __attribute__((ext_vector_type(8))) short short8v;
typedef __attribute__((ext_vector_type(4))) float f32x4;
typedef __attribute__((ext_vector_type(2))) long long2v;

__device__ __forceinline__ short f2bf(float f) {
    unsigned u = __float_as_uint(f);
    u += 0x7fffu + ((u >> 16) & 1u);   // round-to-nearest-even
    return (short)(u >> 16);
}
__device__ __forceinline__ float bf2f(short s) {
    return __uint_as_float(((unsigned)(unsigned short)s) << 16);
}
// pack 4 floats -> 4 OCP e4m3 bytes (HW cvt, RNE+sat)
__device__ __forceinline__ int pk4_fp8(float a, float b, float c, float d) {
    int v = __builtin_amdgcn_cvt_pk_fp8_f32(a, b, 0, false);
    return  __builtin_amdgcn_cvt_pk_fp8_f32(c, d, v, true);
}

// K-interleave permutation: within each 64-k block, store the 8 eight-byte
// MFMA quad-chunks as [A0 B0 A1 B1 A2 B2 A3 B3] so one b128 read at quad*16
// returns {k-step0 frag, k-step1 frag} for mfma_16x16x32_fp8_fp8.
__device__ __forceinline__ int kperm(int k) {
    return (k & ~63) | (((k >> 3) & 3) << 4) | (((k >> 5) & 1) << 3) | (k & 7);
}

// async global->LDS DMA, 16 B/lane; lds dest = wave-uniform base + lane*16
__device__ __forceinline__ void g2lds16(const void* g, void* l) {
    __builtin_amdgcn_global_load_lds(
        (const __attribute__((address_space(1))) void*)g,
        (__attribute__((address_space(3))) void*)l, 16, 0, 0);
}

// ---------------------------------------------------------------------------
// prep_trans: blocks [0, B/4): per-row L2 norm + fp8 A1 emit, one wave per
// row (single global read). Blocks [B/4, B/4+848): weight transpose+cvt.
#define NTB_Z0 272   // 17*16
#define NTB_Z1 256
#define NTB_Z2 256
#define NTB_Z3 64
#define NTB_ALL (NTB_Z0 + NTB_Z1 + NTB_Z2 + NTB_Z3)
#define PREP_BLKS (B_ROWS / 4)

__global__ __launch_bounds__(256) void prep_trans(
    const float* __restrict__ x1, const float* __restrict__ x2,
    const float* __restrict__ gf, char* __restrict__ A1,
    const float* __restrict__ W0, char* __restrict__ Wt0,
    const float* __restrict__ W1, char* __restrict__ Wt1,
    const float* __restrict__ W2, char* __restrict__ Wt2,
    const float* __restrict__ W3, char* __restrict__ Wt3)
{
    __shared__ float T[64][68];
    const int t = threadIdx.x;
    const int bid = blockIdx.x;

    if (bid < PREP_BLKS) {
        const int lane = t & 63;
        const int row = bid * 4 + (t >> 6);
        const size_t rb8 = (size_t)row * E_DIM + lane * 8;
        float4 u0 = *(const float4*)&x1[rb8];
        float4 u1 = *(const float4*)&x1[rb8 + 4];
        float4 v0 = *(const float4*)&x2[rb8];
        float4 v1 = *(const float4*)&x2[rb8 + 4];
        float s1 = u0.x*u0.x + u0.y*u0.y + u0.z*u0.z + u0.w*u0.w
                 + u1.x*u1.x + u1.y*u1.y + u1.z*u1.z + u1.w*u1.w;
        float s2 = v0.x*v0.x + v0.y*v0.y + v0.z*v0.z + v0.w*v0.w
                 + v1.x*v1.x + v1.y*v1.y + v1.z*v1.z + v1.w*v1.w;
        #pragma unroll
        for (int off = 32; off > 0; off >>= 1) {
            s1 += __shfl_xor(s1, off, 64);
            s2 += __shfl_xor(s2, off, 64);
        }
        const float inv1 = SCL_IN / fmaxf(sqrtf(s1), 1e-12f);
        const float inv2 = SCL_IN / fmaxf(sqrtf(s2), 1e-12f);

        const size_t rb = (size_t)row * K1_PAD;
        const int k0 = lane * 8;
        *(int*)&A1[rb + kperm(k0)]           = pk4_fp8(u0.x*inv1, u0.y*inv1, u0.z*inv1, u0.w*inv1);
        *(int*)&A1[rb + kperm(k0 + 4)]       = pk4_fp8(u1.x*inv1, u1.y*inv1, u1.z*inv1, u1.w*inv1);
        *(int*)&A1[rb + kperm(512 + k0)]     = pk4_fp8(v0.x*inv2, v0.y*inv2, v0.z*inv2, v0.w*inv2);
        *(int*)&A1[rb + kperm(512 + k0 + 4)] = pk4_fp8(v1.x*inv2, v1.y*inv2, v1.z*inv2, v1.w*inv2);
        if (lane < 16) {
            const int k = 1024 + lane * 4;   // covers pad 1024..1087
            float a = 0.f, b = 0.f;
            if (k == 1024) { a = gf[(size_t)row * 2 + 0] * SCL_IN;
                             b = gf[(size_t)row * 2 + 1] * SCL_IN; }
            *(int*)&A1[rb + kperm(k)] = pk4_fp8(a, b, 0.f, 0.f);
        }
        return;
    }

    // ---- transpose body ----
    int job = bid - PREP_BLKS;
    const float* W; char* Wt; int K, N, Kpad, k0, n0;
    if (job < NTB_Z0)                 { W = W0; Wt = Wt0; K = K1_RAW; N = H_DIM; Kpad = K1_PAD; k0 = (job % 17) * 64; n0 = (job / 17) * 64; }
    else if (job < NTB_Z0 + NTB_Z1)   { int t2 = job - NTB_Z0;           W = W1; Wt = Wt1; K = H_DIM; N = H_DIM; Kpad = H_DIM; k0 = (t2 & 15) * 64; n0 = (t2 >> 4) * 64; }
    else if (job < NTB_Z0 + NTB_Z1 + NTB_Z2) { int t2 = job - NTB_Z0 - NTB_Z1; W = W2; Wt = Wt2; K = H_DIM; N = H_DIM; Kpad = H_DIM; k0 = (t2 & 15) * 64; n0 = (t2 >> 4) * 64; }
    else                              { int t2 = job - NTB_Z0 - NTB_Z1 - NTB_Z2; W = W3; Wt = Wt3; K = H_DIM; N = P_DIM; Kpad = H_DIM; k0 = (t2 & 15) * 64; n0 = (t2 >> 4) * 64; }

    const int r = t >> 4;          // 0..15
    const int c = (t & 15) << 2;   // 0..60
    #pragma unroll
    for (int rr = 0; rr < 4; ++rr) {
        int k = k0 + r + rr * 16;
        float4 v = (k < K) ? *(const float4*)&W[(size_t)k * N + n0 + c]
                           : make_float4(0.f, 0.f, 0.f, 0.f);
        v.x *= SCL_IN; v.y *= SCL_IN; v.z *= SCL_IN; v.w *= SCL_IN;
        *(float4*)&T[r + rr * 16][c] = v;
    }
    __syncthreads();
    const int n = n0 + (t >> 2);
    const int cn = t >> 2;
    const int ks = (t & 3) << 4;   // 0,16,32,48
    #pragma unroll
    for (int g = 0; g < 2; ++g) {
        int kk = ks + g * 8;
        int lo = pk4_fp8(T[kk+0][cn], T[kk+1][cn], T[kk+2][cn], T[kk+3][cn]);
        int hi = pk4_fp8(T[kk+4][cn], T[kk+5][cn], T[kk+6][cn], T[kk+7][cn]);
        int2 o = { lo, hi };
        int np = k0 + (((kk >> 3) & 3) << 4) + (((kk >> 5) & 1) << 3);
        *(int2*)&Wt[(size_t)n * Kpad + np] = o;
    }
}

// ---------------------------------------------------------------------------
// gemm256h: 256x128-tile fp8 GEMM, 2 blocks/CU, TRIPLE-buffered LDS (72KB),
// ONE barrier per 64-K tile, counted vmcnt(3).
// LDS BANK-CONFLICT SWIZZLE (T2, rule #21 both-sides): quad-chunk q of row r
// lives at slot q ^ ((r>>1)&3). global_load_lds writes linearly, so the
// inverse permutation is applied on the GLOBAL source address
// (chunk = (lane&3) ^ ((lane>>3)&3); row = base16 + (lane>>2) makes
// (row>>1)&3 == (lane>>3)&3 wave-uniformly). Frag reads XOR the same value
// (quad ^ ((m16>>1)&3); i/wm terms contribute multiples of 4 to row>>1).
// Read slots for m16=0..7 become {0,4,1,5,2,6,3,7}: conflict-free.
template <int KA>
__global__ __launch_bounds__(512, 4) void gemm256h(
    const char* __restrict__ A, const char* __restrict__ Bt,
    const float* __restrict__ bias, float cscale,
    short* __restrict__ Cb, int N)
{
    constexpr int NK = KA >> 6;
    static_assert(NK >= 3, "need NK >= 3");

    __shared__ __align__(16) char smem[73728];   // 3 x (A 16KB + B 8KB)

    const int t = threadIdx.x;
    const int w = t >> 6, lane = t & 63;
    const int wu = __builtin_amdgcn_readfirstlane(w);
    const int wm = w & 3, wn = w >> 2;
    const int m16 = lane & 15, quad = lane >> 4;
    const int row0 = blockIdx.x * 256, col0 = blockIdx.y * 128;

    const int gchunk = ((lane & 3) ^ ((lane >> 3) & 3)) << 4;  // pre-swizzled src
    const int qsw    = (quad ^ ((m16 >> 1) & 3)) << 4;         // swizzled read

    const char* AgLo = A  + (size_t)(row0 + wu * 16 + (lane >> 2)) * KA + gchunk;
    const char* AgHi = AgLo + (size_t)128 * KA;
    const char* Bg   = Bt + (size_t)(col0 + wu * 16 + (lane >> 2)) * KA + gchunk;

    auto stage = [&](int kt, int buf) {
        const size_t ko = (size_t)kt << 6;
        char* base = smem + buf * 24576;
        g2lds16(AgLo + ko, base + (wu << 10));
        g2lds16(AgHi + ko, base + 8192 + (wu << 10));
        g2lds16(Bg + ko, base + 16384 + (wu << 10));
    };

    f32x4 acc[4][4];
    #pragma unroll
    for (int i = 0; i < 4; ++i)
        #pragma unroll
        for (int j = 0; j < 4; ++j)
            acc[i][j] = (f32x4){0.f, 0.f, 0.f, 0.f};

    stage(0, 0);
    stage(1, 1);
    int bufr = 0, bufs = 2;

    #pragma unroll 1
    for (int kt = 0; kt < NK; ++kt) {
        // tile kt's 3 own loads complete; tile kt+1's 3 may stay in flight.
        if (kt + 1 < NK) asm volatile("s_waitcnt vmcnt(3)" ::: "memory");
        else             asm volatile("s_waitcnt vmcnt(0)" ::: "memory");
        __builtin_amdgcn_s_barrier();

        const char* base = smem + bufr * 24576;
        bufr = (bufr == 2) ? 0 : bufr + 1;
        long2v a[4], b[4];
        #pragma unroll
        for (int i = 0; i < 4; ++i)
            a[i] = *(const long2v*)&base[(wm * 64 + i * 16 + m16) * 64 + qsw];
        #pragma unroll
        for (int j = 0; j < 4; ++j)
            b[j] = *(const long2v*)&base[16384 + (wn * 64 + j * 16 + m16) * 64 + qsw];

        if (kt + 2 < NK) {
            stage(kt + 2, bufs);
            bufs = (bufs == 2) ? 0 : bufs + 1;
        }

        __builtin_amdgcn_s_setprio(1);
        #pragma unroll
        for (int i = 0; i < 4; ++i)
            #pragma unroll
            for (int j = 0; j < 4; ++j) {
                acc[i][j] = __builtin_amdgcn_mfma_f32_16x16x32_fp8_fp8(
                    a[i][0], b[j][0], acc[i][j], 0, 0, 0);
                acc[i][j] = __builtin_amdgcn_mfma_f32_16x16x32_fp8_fp8(
                    a[i][1], b[j][1], acc[i][j], 0, 0, 0);
            }
        __builtin_amdgcn_s_setprio(0);
    }

    // ---- staged epilogue: 2 row-halves, coalesced short8 stores ----
    float bj[4];
    #pragma unroll
    for (int j = 0; j < 4; ++j)
        bj[j] = bias[col0 + wn * 64 + j * 16 + m16];

    short* Cs = (short*)smem;   // [128][136]
    #pragma unroll
    for (int ch = 0; ch < 2; ++ch) {
        __syncthreads();
        if ((wm >> 1) == ch) {
            #pragma unroll
            for (int i = 0; i < 4; ++i) {
                const int rbase = (wm & 1) * 64 + i * 16 + quad * 4;
                #pragma unroll
                for (int j = 0; j < 4; ++j) {
                    const int cc = wn * 64 + j * 16 + m16;
                    #pragma unroll
                    for (int r = 0; r < 4; ++r)
                        Cs[(rbase + r) * 136 + cc] = f2bf(acc[i][j][r] * cscale + bj[j]);
                }
            }
        }
        __syncthreads();
        #pragma unroll
        for (int p = 0; p < 4; ++p) {
            const int idx = p * 512 + t;
            const int r = idx >> 4, c8 = idx & 15;
            short8v v = *(const short8v*)&Cs[r * 136 + c8 * 8];
            *(short8v*)&Cb[(size_t)(row0 + ch * 128 + r) * N + col0 + c8 * 8] = v;
        }
    }
}

// ---------------------------------------------------------------------------
// LN+ReLU, ONE WAVE PER ROW (4 rows/block). bf16 in, fp8(kperm) out.
// Residual carry reconstructed from the PREVIOUS fp8 act (in-place buffer).
template <int HAS_RES>
__global__ __launch_bounds__(256) void ln_relu_f8(
    const short* __restrict__ X, const float* __restrict__ gamma,
    const float* __restrict__ beta, char* __restrict__ act)
{
    const int row  = blockIdx.x * 4 + (threadIdx.x >> 6);
    const int lane = threadIdx.x & 63;
    const size_t base = (size_t)row * H_DIM;

    float y[4][4];
    float s = 0.f, ss = 0.f;
    #pragma unroll
    for (int j = 0; j < 4; ++j) {
        const int idx = j * 256 + lane * 4;
        short4v xb = *(const short4v*)&X[base + idx];
        #pragma unroll
        for (int e = 0; e < 4; ++e) {
            float xv = bf2f(xb[e]);
            y[j][e] = xv;
            s += xv; ss += xv * xv;
        }
    }
    #pragma unroll
    for (int off = 32; off > 0; off >>= 1) {
        s  += __shfl_xor(s,  off, 64);
        ss += __shfl_xor(ss, off, 64);
    }
    const float m = s * (1.f / H_DIM);
    const float var = fmaxf(ss * (1.f / H_DIM) - m * m, 0.f);
    const float r = 1.f / sqrtf(var + 1e-5f);

    #pragma unroll
    for (int j = 0; j < 4; ++j) {
        const int idx = j * 256 + lane * 4;
        float4 g  = *(const float4*)&gamma[idx];
        float4 be = *(const float4*)&beta[idx];
        float gv[4] = { g.x, g.y, g.z, g.w };
        float bv[4] = { be.x, be.y, be.z, be.w };
        #pragma unroll
        for (int e = 0; e < 4; ++e)
            y[j][e] = fmaxf((y[j][e] - m) * r * gv[e] + bv[e], 0.f);
        if constexpr (HAS_RES) {
            const int rv = *(const int*)&act[base + kperm(idx)];
            y[j][0] += __builtin_amdgcn_cvt_f32_fp8(rv, 0);
            y[j][1] += __builtin_amdgcn_cvt_f32_fp8(rv, 1);
            y[j][2] += __builtin_amdgcn_cvt_f32_fp8(rv, 2);
            y[j][3] += __builtin_amdgcn_cvt_f32_fp8(rv, 3);
        }
        *(int*)&act[base + kperm(idx)] = pk4_fp8(y[j][0], y[j][1], y[j][2], y[j][3]);
    }
}

// ---------------------------------------------------------------------------
// gemm_fcls: final_proj GEMM (64x256 tile, full N=P_DIM) + fused final LN +
// classifier + gender mask. Triple-buffered, counted vmcnt(2), ONE
// barrier/tile, same T2 swizzle as gemm256h.
__global__ __launch_bounds__(512, 2) void gemm_fcls(
    const char* __restrict__ A, const char* __restrict__ Bt,
    const float* __restrict__ bias, const float* __restrict__ gamma,
    const float* __restrict__ beta, const float* __restrict__ Wc,
    const float* __restrict__ bc, const float* __restrict__ gfeat,
    float* __restrict__ outp)
{
    __shared__ __align__(16) char smem[61440];   // 3 x (A 4KB + B 16KB)

    const int t = threadIdx.x;
    const int w = t >> 6, lane = t & 63;
    const int wu = __builtin_amdgcn_readfirstlane(w);
    const int wm = w & 1, wn = w >> 1;
    const int m16 = lane & 15, quad = lane >> 4;
    const int row0 = blockIdx.x * 64;

    const int gchunk = ((lane & 3) ^ ((lane >> 3) & 3)) << 4;  // pre-swizzled src
    const int qsw    = (quad ^ ((m16 >> 1) & 3)) << 4;         // swizzled read

    const char* Ag  = A  + (size_t)(row0 + (wu & 3) * 16 + (lane >> 2)) * H_DIM + gchunk;
    const char* Bg0 = Bt + (size_t)(wu * 32 + (lane >> 2)) * H_DIM + gchunk;
    const char* Bg1 = Bg0 + (size_t)16 * H_DIM;

    auto stage = [&](int kt, int buf) {
        const size_t ko = (size_t)kt << 6;
        char* base = smem + buf * 20480;
        if (wu < 4) g2lds16(Ag + ko, base + ((wu & 3) << 10));
        g2lds16(Bg0 + ko, base + 4096 + wu * 2048);
        g2lds16(Bg1 + ko, base + 4096 + wu * 2048 + 1024);
    };

    f32x4 acc[2][4];
    #pragma unroll
    for (int i = 0; i < 2; ++i)
        #pragma unroll
        for (int j = 0; j < 4; ++j)
            acc[i][j] = (f32x4){0.f, 0.f, 0.f, 0.f};

    stage(0, 0);
    stage(1, 1);
    int bufr = 0, bufs = 2;

    #pragma unroll 1
    for (int kt = 0; kt < 16; ++kt) {
        if (kt + 1 < 16) asm volatile("s_waitcnt vmcnt(2)" ::: "memory");
        else             asm volatile("s_waitcnt vmcnt(0)" ::: "memory");
        __builtin_amdgcn_s_barrier();

        const char* As = smem + bufr * 20480;
        const char* Bs = As + 4096;
        bufr = (bufr == 2) ? 0 : bufr + 1;
        long2v af[2], bf[4];
        #pragma unroll
        for (int i = 0; i < 2; ++i)
            af[i] = *(const long2v*)&As[(wm * 32 + i * 16 + m16) * 64 + qsw];
        #pragma unroll
        for (int j = 0; j < 4; ++j)
            bf[j] = *(const long2v*)&Bs[(wn * 64 + j * 16 + m16) * 64 + qsw];

        if (kt + 2 < 16) {
            stage(kt + 2, bufs);
            bufs = (bufs == 2) ? 0 : bufs + 1;
        }

        __builtin_amdgcn_s_setprio(1);
        #pragma unroll
        for (int i = 0; i < 2; ++i)
            #pragma unroll
            for (int j = 0; j < 4; ++j) {
                acc[i][j] = __builtin_amdgcn_mfma_f32_16x16x32_fp8_fp8(
                    af[i][0], bf[j][0], acc[i][j], 0, 0, 0);
                acc[i][j] = __builtin_amdgcn_mfma_f32_16x16x32_fp8_fp8(
                    af[i][1], bf[j][1], acc[i][j], 0, 0, 0);
            }
        __builtin_amdgcn_s_setprio(0);
    }
    __syncthreads();   // all LDS reads done before smem reuse

    float bj[4];
    #pragma unroll
    for (int j = 0; j < 4; ++j)
        bj[j] = bias[wn * 64 + j * 16 + m16];

    short* xs  = (short*)smem;                 // [64][264] bf16
    float* red = (float*)(smem + 33792);       // [8][64][2]
    float* mr  = (float*)(smem + 37888);       // [64][2]

    #pragma unroll
    for (int i = 0; i < 2; ++i)
        #pragma unroll
        for (int r = 0; r < 4; ++r) {
            float s = 0.f, ss = 0.f;
            #pragma unroll
            for (int j = 0; j < 4; ++j) {
                float x = acc[i][j][r] * INV_G + bj[j];
                s += x; ss += x * x;
            }
            #pragma unroll
            for (int off = 1; off <= 8; off <<= 1) {
                s  += __shfl_xor(s,  off, 64);
                ss += __shfl_xor(ss, off, 64);
            }
            if (m16 == 0) {
                const int ri = wm * 32 + i * 16 + quad * 4 + r;
                red[(w * 64 + ri) * 2 + 0] = s;
                red[(w * 64 + ri) * 2 + 1] = ss;
            }
        }
    __syncthreads();
    if (t < 64) {
        const int wmRow = t >> 5;
        float s = 0.f, ss = 0.f;
        #pragma unroll
        for (int q = 0; q < 4; ++q) {
            const int ww = wmRow + 2 * q;
            s  += red[(ww * 64 + t) * 2 + 0];
            ss += red[(ww * 64 + t) * 2 + 1];
        }
        const float mm = s * (1.f / P_DIM);
        mr[t * 2 + 0] = mm;
        mr[t * 2 + 1] = 1.f / sqrtf(fmaxf(ss * (1.f / P_DIM) - mm * mm, 0.f) + 1e-5f);
    }
    #pragma unroll
    for (int i = 0; i < 2; ++i)
        #pragma unroll
        for (int j = 0; j < 4; ++j)
            #pragma unroll
            for (int r = 0; r < 4; ++r)
                xs[(wm * 32 + i * 16 + quad * 4 + r) * 264 + wn * 64 + j * 16 + m16] =
                    f2bf(acc[i][j][r] * INV_G + bj[j]);
    __syncthreads();

    #pragma unroll 2
    for (int rr = 0; rr < 8; ++rr) {
        const int row = w * 8 + rr;
        const float mm = mr[row * 2 + 0], rs = mr[row * 2 + 1];
        const int c = lane * 4;
        short4v xv = *(const short4v*)&xs[row * 264 + c];
        float4 ga = *(const float4*)&gamma[c];
        float4 ba = *(const float4*)&beta[c];
        const float gv[4] = {ga.x, ga.y, ga.z, ga.w};
        const float bvv[4] = {ba.x, ba.y, ba.z, ba.w};
        float p[7] = {0.f, 0.f, 0.f, 0.f, 0.f, 0.f, 0.f};
        #pragma unroll
        for (int e = 0; e < 4; ++e) {
            const float yv = fmaxf((bf2f(xv[e]) - mm) * rs * gv[e] + bvv[e], 0.f);
            const float* wr = &Wc[(c + e) * 7];
            #pragma unroll
            for (int c7 = 0; c7 < 7; ++c7) p[c7] += yv * wr[c7];
        }
        #pragma unroll
        for (int off = 32; off > 0; off >>= 1)
            #pragma unroll
            for (int c7 = 0; c7 < 7; ++c7) p[c7] += __shfl_xor(p[c7], off, 64);
        if (lane == 0) {
            const size_t gr = (size_t)(row0 + row);
            int g1 = (gfeat[gr * 2 + 0] != 0.f);
            int g2 = (gfeat[gr * 2 + 1] != 0.f);
            unsigned bits = (g1 == g2) ? (g1 ? 0x24u : 0x12u) : 0x49u;
            #pragma unroll
            for (int c7 = 0; c7 < 7; ++c7)
                outp[gr * 7 + c7] = ((bits >> c7) & 1u) ? p[c7] + bc[c7] : NEG_BIG;
        }
    }
}

// ---------------------------------------------------------------------------
extern "C" void kernel_launch(void* const* d_in, const int* in_sizes, int n_in,
                              void* d_out, int out_size, void* d_ws, size_t ws_size,
                              hipStream_t stream)
{
    const float* x1   = (const float*)d_in[0];
    const float* x2   = (const float*)d_in[1];
    const float* gf   = (const float*)d_in[2];
    const float* W_in = (const float*)d_in[3];
    const float* b_in = (const float*)d_in[4];
    const float* g_in = (const float*)d_in[5];
    const float* be_in = (const float*)d_in[6];
    const float* W_r1 = (const float*)d_in[7];
    const float* b_r1 = (const float*)d_in[8];
    const float* g_r1 = (const float*)d_in[9];
    const float* be_r1 = (const float*)d_in[10];
    const float* W_r2 = (const float*)d_in[11];
    const float* b_r2 = (const float*)d_in[12];
    const float* g_r2 = (const float*)d_in[13];
    const float* be_r2 = (const float*)d_in[14];
    const float* W_f  = (const float*)d_in[15];
    const float* b_f  = (const float*)d_in[16];
    const float* g_f  = (const float*)d_in[17];
    const float* be_f = (const float*)d_in[18];
    const float* W_c  = (const float*)d_in[19];
    const float* b_c  = (const float*)d_in[20];
    float* out = (float*)d_out;

    const int B = B_ROWS;

    // ---- workspace layout ----
    char* p = (char*)d_ws;
    char*  A1    = p;            p += (size_t)B * K1_PAD;     // fp8, stride 1088
    char*  act   = p;            p += (size_t)B * H_DIM;      // fp8, stride 1024 (in-place)
    short* preb  = (short*)p;    p += (size_t)B * H_DIM * 2;  // bf16 GEMM out
    char*  Wt_in = p;            p += (size_t)H_DIM * K1_PAD;
    char*  Wt_r1 = p;            p += (size_t)H_DIM * H_DIM;
    char*  Wt_r2 = p;            p += (size_t)H_DIM * H_DIM;
    char*  Wt_f  = p;            p += (size_t)P_DIM * H_DIM;

    // 1) prep (single-pass L2 norm + fp8 A1) + all weight transposes
    prep_trans<<<PREP_BLKS + NTB_ALL, 256, 0, stream>>>(
        x1, x2, gf, A1,
        W_in, Wt_in, W_r1, Wt_r1, W_r2, Wt_r2, W_f, Wt_f);

    // 2) input_proj GEMM + LN1 -> act fp8
    gemm256h<K1_PAD><<<dim3(B / 256, H_DIM / 128), 512, 0, stream>>>(
        A1, Wt_in, b_in, INV_G1, preb, H_DIM);
    ln_relu_f8<0><<<B / 4, 256, 0, stream>>>(preb, g_in, be_in, act);

    // 3) residual block 1 (residual carried in fp8 act, in-place)
    gemm256h<H_DIM><<<dim3(B / 256, H_DIM / 128), 512, 0, stream>>>(
        act, Wt_r1, b_r1, INV_G, preb, H_DIM);
    ln_relu_f8<1><<<B / 4, 256, 0, stream>>>(preb, g_r1, be_r1, act);

    // 4) residual block 2
    gemm256h<H_DIM><<<dim3(B / 256, H_DIM / 128), 512, 0, stream>>>(
        act, Wt_r2, b_r2, INV_G, preb, H_DIM);
    ln_relu_f8<1><<<B / 4, 256, 0, stream>>>(preb, g_r2, be_r2, act);

    // 5) final_proj + final LN + classifier + gender mask (fused)
    gemm_fcls<<<B / 64, 512, 0, stream>>>(
        act, Wt_f, b_f, g_f, be_f, W_c, b_c, gf, out);
}